// Round 22
// baseline (247.794 us; speedup 1.0000x reference)
//
#include <hip/hip_runtime.h>
#include <stdint.h>

// ---------------------------------------------------------------------------
// TransformerBlock: pre-LN MHA + pre-LN FFN(GELU), bf16 MFMA internals.
// B=2 S=2048 D=1024 H=16 dk=64 Dff=4096.
// R22 = R21 (best, 240.6us) + FFN2 single-pass: R21's deep-lead erased the
// under-occupancy penalty that motivated split-K (Wo now ~740 TF at
// 1 blk/CU).  FFN2 runs gridDim.z=1, Kc=4096 (64 K-tiles), epilogue
// out += v + bias (EPI5); reduce_add dispatch and 64MB of partial/reduce
// traffic removed.  Same fetch volume, same per-element summation order.
// GEMM schedules: gemm_256 (R20 4-phase, 2-tile lead) for QKV/FFN1;
// gemm_pipe (R21 deep-lead monolithic-MFMA) for Wo/FFN2.
// Attention R10 form (58us plateau: TLP refuted R9/R12/R13, ILP R11).
// Workspace layout (64 MB):
//   [ 0MB) h_buf [4096,1024]bf16 (h1/attn/h2)
//   [ 8MB) wqkv_t[3072,1024]bf16
//   [14MB) wo_t  [1024,1024]bf16
//   [16MB) w1_t  [4096,1024]bf16
//   [24MB) w2_t  [1024,4096]bf16
//   [32MB) q_attn 8MB / k_attn 8MB / v_attn 8MB } ffn1 [4096,4096] overlaps
// d_out doubles as x2 (attn residual) between the Wo GEMM and FFN2.
// ---------------------------------------------------------------------------

typedef __attribute__((ext_vector_type(8))) short bf16x8;
typedef __attribute__((ext_vector_type(4))) float f32x4;
typedef __attribute__((ext_vector_type(16))) float f32x16;
typedef __attribute__((ext_vector_type(4))) unsigned short u16x4;
typedef __attribute__((ext_vector_type(4))) unsigned int u32x4;

#define DEV __device__ __forceinline__

static constexpr int DM   = 1024;
static constexpr int DFF  = 4096;
static constexpr int NH   = 16;
static constexpr int DKH  = 64;
static constexpr int SEQ  = 2048;
static constexpr int NBAT = 2;
static constexpr int NTOK = NBAT * SEQ;  // 4096

DEV unsigned short f2bf(float f) {
  union { float f; unsigned int u; } v; v.f = f;
  unsigned int u = v.u;
  return (unsigned short)((u + 0x7fffu + ((u >> 16) & 1u)) >> 16);
}

DEV void gload_lds16(const unsigned short* g, unsigned short* l) {
  __builtin_amdgcn_global_load_lds(
      (const __attribute__((address_space(1))) unsigned int*)g,
      (__attribute__((address_space(3))) unsigned int*)l, 16, 0, 0);
}

// A&S 7.1.26 erf (|err| <= 1.5e-7), exact-GELU epilogue helper.
DEV float fast_gelu(float x) {
  const float z = fabsf(x) * 0.70710678118654752f;
  const float t = __builtin_amdgcn_rcpf(1.0f + 0.3275911f * z);
  float p = 1.061405429f;
  p = p * t - 1.453152027f;
  p = p * t + 1.421413741f;
  p = p * t - 0.284496736f;
  p = p * t + 0.254829592f;
  p = p * t;
  float erfv = 1.0f - p * __expf(-z * z);
  erfv = copysignf(erfv, x);
  return 0.5f * x * (1.0f + erfv);
}

// ---------------------------------------------------------------------------
// LayerNorm body: x fp32 [rows,1024] -> bf16 out; one 256-thr block per row.
// ---------------------------------------------------------------------------
DEV void ln_body(const float* __restrict__ x, const float* __restrict__ g,
                 const float* __restrict__ be, unsigned short* __restrict__ out,
                 int row, float* rs_, float* rq_) {
  const int t = threadIdx.x;
  const int lane = t & 63, w = t >> 6;
  const float4* xr = (const float4*)(x + (size_t)row * DM);
  float4 v = xr[t];
  float s  = v.x + v.y + v.z + v.w;
  float s2 = v.x * v.x + v.y * v.y + v.z * v.z + v.w * v.w;
#pragma unroll
  for (int off = 32; off; off >>= 1) {
    s  += __shfl_down(s, off);
    s2 += __shfl_down(s2, off);
  }
  if (lane == 0) { rs_[w] = s; rq_[w] = s2; }
  __syncthreads();
  float fs = rs_[0] + rs_[1] + rs_[2] + rs_[3];
  float fq = rq_[0] + rq_[1] + rq_[2] + rq_[3];
  float mu = fs * (1.0f / DM);
  float var = fq * (1.0f / DM) - mu * mu;
  float rstd = rsqrtf(var + 1e-5f);
  float4 gv = ((const float4*)g)[t];
  float4 bv = ((const float4*)be)[t];
  u16x4 o;
  o[0] = f2bf((v.x - mu) * rstd * gv.x + bv.x);
  o[1] = f2bf((v.y - mu) * rstd * gv.y + bv.y);
  o[2] = f2bf((v.z - mu) * rstd * gv.z + bv.z);
  o[3] = f2bf((v.w - mu) * rstd * gv.w + bv.w);
  *(u16x4*)(out + (size_t)row * DM + t * 4) = o;
}

__global__ __launch_bounds__(256) void ln_kernel(
    const float* __restrict__ x, const float* __restrict__ g,
    const float* __restrict__ be, unsigned short* __restrict__ out) {
  __shared__ float rs_[4], rq_[4];
  ln_body(x, g, be, out, blockIdx.x, rs_, rq_);
}

// ---------------------------------------------------------------------------
// Fused prelude: blocks [0,3072) = weight transpose; [3072,7168) = LN1 rows.
// ---------------------------------------------------------------------------
__global__ __launch_bounds__(256) void prep_kernel(
    const float* __restrict__ x, const float* __restrict__ g1,
    const float* __restrict__ be1, unsigned short* __restrict__ lnout,
    const float* __restrict__ Wq, const float* __restrict__ Wk,
    const float* __restrict__ Wv, const float* __restrict__ Wo,
    const float* __restrict__ W1, const float* __restrict__ W2,
    unsigned short* __restrict__ wqkv_t, unsigned short* __restrict__ wo_t,
    unsigned short* __restrict__ w1_t, unsigned short* __restrict__ w2_t) {
  __shared__ float lds[64][65];
  __shared__ float rs_[4], rq_[4];
  const int t = blockIdx.x;
  if (t >= 3072) {
    ln_body(x, g1, be1, lnout, t - 3072, rs_, rq_);
    return;
  }
  const float* inb; unsigned short* outb; int in_ld, out_ld;
  if (t < 768) {            // wqkv_t[n=which*1024+h*64+kk][d] = W[h][d][kk]
    const int slice = t >> 4, tin = t & 15;
    const int which = slice >> 4, h = slice & 15;
    const float* W = (which == 0) ? Wq : (which == 1) ? Wk : Wv;
    inb = W + (size_t)((h << 10) + (tin << 6)) * 64;
    in_ld = 64;
    outb = wqkv_t + ((size_t)((which << 10) + (h << 6)) << 10) + (tin << 6);
    out_ld = 1024;
  } else if (t < 1024) {    // wo_t[n][d] = Wo[d][n]
    const int tt = t - 768, tr = tt >> 4, tc = tt & 15;
    inb = Wo + (size_t)(tc << 6) * 1024 + (tr << 6); in_ld = 1024;
    outb = wo_t + (size_t)(tr << 6) * 1024 + (tc << 6); out_ld = 1024;
  } else if (t < 2048) {    // w1_t[n(4096)][d] = W1[d][n]
    const int tt = t - 1024, tr = tt >> 4, tc = tt & 15;
    inb = W1 + (size_t)(tc << 6) * 4096 + (tr << 6); in_ld = 4096;
    outb = w1_t + (size_t)(tr << 6) * 1024 + (tc << 6); out_ld = 1024;
  } else {                  // w2_t[n(1024)][s(4096)] = W2[s][n]
    const int tt = t - 2048, tr = tt >> 6, tc = tt & 63;
    inb = W2 + (size_t)(tc << 6) * 1024 + (tr << 6); in_ld = 1024;
    outb = w2_t + (size_t)(tr << 6) * 4096 + (tc << 6); out_ld = 4096;
  }
  const int j = threadIdx.x & 63, i0 = threadIdx.x >> 6;
#pragma unroll
  for (int p = 0; p < 16; ++p) {
    const int i = i0 + p * 4;
    lds[j][i] = inb[(size_t)i * in_ld + j];
  }
  __syncthreads();
#pragma unroll
  for (int p = 0; p < 16; ++p) {
    const int r = i0 + p * 4;
    outb[(size_t)r * out_ld + j] = f2bf(lds[r][j]);
  }
}

// ---------------------------------------------------------------------------
struct EpiArgs {
  unsigned short* q;     // EPI0 (frag-stream)
  unsigned short* k;     // EPI0 (frag-stream)
  unsigned short* vt;    // EPI0 (frag-stream, kv bit2<->3 folded)
  unsigned short* ob16;  // EPI2
  float* of32;           // EPI1 / EPI5
  const float* bias;     // EPI2 / EPI5
  const float* resid;    // EPI1
};

template <int EPI>
DEV void epilogue_elem(float v, int row, int col, int N, const EpiArgs& ep) {
  if constexpr (EPI == 0) {  // QKV -> fragment-stream scratch layouts
    const int bb = row >> 11, rr = row & 2047;
    if (col < 1024) {        // Q (pre-scaled by log2e/sqrt(dk) -> exp2 domain)
      const int hh = col >> 6, dk = col & 63;
      const int kk = dk >> 4, h8 = (dk >> 3) & 1, e = dk & 7;
      const int qblk = rr >> 5, l31 = rr & 31;
      ep.q[((size_t)(bb * NH + hh) * 64 + qblk) * 2048 + kk * 512 +
           (h8 * 32 + l31) * 8 + e] = f2bf(v * 0.18033688011112042f);
    } else if (col < 2048) { // K
      const int c = col - 1024;
      const int hh = c >> 6, dk = c & 63;
      const int kk = dk >> 4, h8 = (dk >> 3) & 1, e = dk & 7;
      const int kvblk = rr >> 5, l31 = rr & 31;
      ep.k[((size_t)(bb * NH + hh) * 64 + kvblk) * 2048 + kk * 512 +
           (h8 * 32 + l31) * 8 + e] = f2bf(v);
    } else {                 // V (kv bit2<->3 swizzle folded in)
      const int c = col - 2048, hh = c >> 6, dd = c & 63;
      const int ssw = (rr & ~12) | ((rr & 4) << 1) | ((rr & 8) >> 1);
      const int t64 = ssw >> 6, w = (ssw >> 4) & 3;
      const int h8 = (ssw >> 3) & 1, e = ssw & 7;
      const int dblk = dd >> 5, l31 = dd & 31;
      ep.vt[(((size_t)(bb * NH + hh) * 32 + t64) * 8 + dblk * 4 + w) * 512 +
            (h8 * 32 + l31) * 8 + e] = f2bf(v);
    }
  } else if constexpr (EPI == 1) {  // Wo: + residual -> fp32 (x2 into d_out)
    const size_t idx = (size_t)row * N + col;
    ep.of32[idx] = v + ep.resid[idx];
  } else if constexpr (EPI == 2) {  // + bias, exact GELU (A&S poly) -> bf16
    ep.ob16[(size_t)row * N + col] = f2bf(fast_gelu(v + ep.bias[col]));
  } else {  // EPI 5: FFN2 single-pass: out += v + bias (out holds x2)
    const size_t idx = (size_t)row * N + col;
    ep.of32[idx] = ep.of32[idx] + v + ep.bias[col];
  }
}

// ---------------------------------------------------------------------------
// gemm_256 (R20): 256x256 tile, 8 waves, BK=64, 2-tile prefetch lead,
// 4 compute phases (Q0..Q3), tile T's P4 stages tile T+2.
// ---------------------------------------------------------------------------
template <int EPI>
__global__ __launch_bounds__(512, 2) void gemm_256(
    const unsigned short* __restrict__ A, const unsigned short* __restrict__ Bt,
    int N, int K, int ldk, EpiArgs ep) {
  __shared__ __align__(16) unsigned short Als[2][256 * 64];
  __shared__ __align__(16) unsigned short Bls[2][256 * 64];
  const int t = threadIdx.x, lane = t & 63, wave = t >> 6;
  const int wm = wave >> 2, wn = wave & 3;
  const int g = lane >> 4, r16 = lane & 15;
  const int nx = gridDim.x, nwg = nx * gridDim.y;
  int wgid = blockIdx.y * nx + blockIdx.x;
  wgid = (wgid & 7) * (nwg >> 3) + (wgid >> 3);
  const int m0 = (wgid / nx) * 256, n0 = (wgid % nx) * 256;

  f32x4 acc[8][4];
  const f32x4 z4 = {0.f, 0.f, 0.f, 0.f};
#pragma unroll
  for (int i = 0; i < 8; ++i)
#pragma unroll
    for (int j = 0; j < 4; ++j) acc[i][j] = z4;

  auto stage_half = [&](int b, int k0, int h) {
#pragma unroll
    for (int i = 0; i < 2; ++i) {
      const int c = i * 512 + t;
      const int row = c >> 3;
      const int sc = ((c & 7) ^ (row & 7)) * 8;
      const int dofs = ((h & 1) << 13) + (i * 512 + (wave << 6)) * 8;
      if (h < 2)
        gload_lds16(A + (size_t)(m0 + ((h & 1) << 7) + row) * ldk + k0 + sc,
                    &Als[b][dofs]);
      else
        gload_lds16(Bt + (size_t)(n0 + ((h & 1) << 7) + row) * ldk + k0 + sc,
                    &Bls[b][dofs]);
    }
  };
  auto stage_tile = [&](int b, int k0) {
#pragma unroll
    for (int h = 0; h < 4; ++h) stage_half(b, k0, h);
  };

  const int NT = K >> 6;
  stage_tile(0, 0);
  if (NT > 1) {
    stage_tile(1, 64);
    asm volatile("s_waitcnt vmcnt(8)" ::: "memory");
  } else {
    asm volatile("s_waitcnt vmcnt(0)" ::: "memory");
  }
  __builtin_amdgcn_s_barrier();

  bf16x8 Af[4][2], Bl[2][2], Bh[2][2];
  for (int T = 0; T < NT; ++T) {
    const int cur = T & 1;
    // ---- P1: ds_read A-low + B-low; MFMA Q0 ----
#pragma unroll
    for (int mf = 0; mf < 4; ++mf) {
      const int row = (wm << 7) + (mf << 4) + r16;
#pragma unroll
      for (int ks = 0; ks < 2; ++ks)
        Af[mf][ks] = *(const bf16x8*)
            &Als[cur][row * 64 + ((((ks << 2) | g) ^ (row & 7)) << 3)];
    }
#pragma unroll
    for (int ni = 0; ni < 2; ++ni) {
      const int row = (wn << 6) + (ni << 4) + r16;
#pragma unroll
      for (int ks = 0; ks < 2; ++ks)
        Bl[ni][ks] = *(const bf16x8*)
            &Bls[cur][row * 64 + ((((ks << 2) | g) ^ (row & 7)) << 3)];
    }
    asm volatile("s_waitcnt lgkmcnt(0)" ::: "memory");
    __builtin_amdgcn_sched_barrier(0);
    __builtin_amdgcn_s_setprio(1);
#pragma unroll
    for (int ks = 0; ks < 2; ++ks)
#pragma unroll
      for (int mf = 0; mf < 4; ++mf)
#pragma unroll
        for (int ni = 0; ni < 2; ++ni)
          acc[mf][ni] = __builtin_amdgcn_mfma_f32_16x16x32_bf16(
              Af[mf][ks], Bl[ni][ks], acc[mf][ni], 0, 0, 0);
    __builtin_amdgcn_s_setprio(0);
    __builtin_amdgcn_s_barrier();
    // ---- P2: ds_read B-high; MFMA Q1 ----
#pragma unroll
    for (int ni = 0; ni < 2; ++ni) {
      const int row = (wn << 6) + ((2 + ni) << 4) + r16;
#pragma unroll
      for (int ks = 0; ks < 2; ++ks)
        Bh[ni][ks] = *(const bf16x8*)
            &Bls[cur][row * 64 + ((((ks << 2) | g) ^ (row & 7)) << 3)];
    }
    asm volatile("s_waitcnt lgkmcnt(0)" ::: "memory");
    __builtin_amdgcn_sched_barrier(0);
    __builtin_amdgcn_s_setprio(1);
#pragma unroll
    for (int ks = 0; ks < 2; ++ks)
#pragma unroll
      for (int mf = 0; mf < 4; ++mf)
#pragma unroll
        for (int ni = 0; ni < 2; ++ni)
          acc[mf][2 + ni] = __builtin_amdgcn_mfma_f32_16x16x32_bf16(
              Af[mf][ks], Bh[ni][ks], acc[mf][2 + ni], 0, 0, 0);
    __builtin_amdgcn_s_setprio(0);
    __builtin_amdgcn_s_barrier();
    // ---- P3: ds_read A-high (overwrites Af); MFMA Q2 ----
#pragma unroll
    for (int mf = 0; mf < 4; ++mf) {
      const int row = (wm << 7) + ((4 + mf) << 4) + r16;
#pragma unroll
      for (int ks = 0; ks < 2; ++ks)
        Af[mf][ks] = *(const bf16x8*)
            &Als[cur][row * 64 + ((((ks << 2) | g) ^ (row & 7)) << 3)];
    }
    asm volatile("s_waitcnt lgkmcnt(0)" ::: "memory");
    __builtin_amdgcn_sched_barrier(0);
    __builtin_amdgcn_s_setprio(1);
#pragma unroll
    for (int ks = 0; ks < 2; ++ks)
#pragma unroll
      for (int mf = 0; mf < 4; ++mf)
#pragma unroll
        for (int ni = 0; ni < 2; ++ni)
          acc[4 + mf][ni] = __builtin_amdgcn_mfma_f32_16x16x32_bf16(
              Af[mf][ks], Bl[ni][ks], acc[4 + mf][ni], 0, 0, 0);
    __builtin_amdgcn_s_setprio(0);
    __builtin_amdgcn_s_barrier();
    // ---- P4: issue tile T+2 (into T's buffer); MFMA Q3 ----
    if (T + 2 < NT) stage_tile(cur, (T + 2) << 6);
    __builtin_amdgcn_s_setprio(1);
#pragma unroll
    for (int ks = 0; ks < 2; ++ks)
#pragma unroll
      for (int mf = 0; mf < 4; ++mf)
#pragma unroll
        for (int ni = 0; ni < 2; ++ni)
          acc[4 + mf][2 + ni] = __builtin_amdgcn_mfma_f32_16x16x32_bf16(
              Af[mf][ks], Bh[ni][ks], acc[4 + mf][2 + ni], 0, 0, 0);
    __builtin_amdgcn_s_setprio(0);
    if (T + 1 < NT)
      asm volatile("s_waitcnt vmcnt(8)" ::: "memory");
    __builtin_amdgcn_s_barrier();
  }
#pragma unroll
  for (int mf = 0; mf < 8; ++mf)
#pragma unroll
    for (int nf = 0; nf < 4; ++nf)
#pragma unroll
      for (int r = 0; r < 4; ++r)
        epilogue_elem<EPI>(acc[mf][nf][r],
                           m0 + (wm << 7) + (mf << 4) + (g << 2) + r,
                           n0 + (wn << 6) + (nf << 4) + r16, N, ep);
}

// ---------------------------------------------------------------------------
// Pipelined GEMM (128^2 tile, BK=64, LDS dbuf) -- Wo / FFN2 (single-pass).
// R21 deep lead: prologue stages tiles 0,1.  Per tile: vmcnt(8|0) ->
// B1 -> ds_read x16 -> lgkmcnt(0) -> B2 (reads done) -> stage(T+2 into
// buf[cur]) -> 32 MFMA (monolithic).
// ---------------------------------------------------------------------------
template <int EPI>
__global__ __launch_bounds__(256) void gemm_pipe(
    const unsigned short* __restrict__ A, const unsigned short* __restrict__ Bt,
    int N, int Kc, int ldk, EpiArgs ep) {
  __shared__ __align__(16) unsigned short Als[2][128 * 64];
  __shared__ __align__(16) unsigned short Bls[2][128 * 64];
  const int t = threadIdx.x, lane = t & 63, wave = t >> 6;
  const int wm = wave >> 1, wn = wave & 1;
  const int g = lane >> 4, r16 = lane & 15;
  const int nx = gridDim.x;
  const int nwg = nx * gridDim.y;
  int wgid = blockIdx.y * nx + blockIdx.x;
  wgid = (wgid & 7) * (nwg >> 3) + (wgid >> 3);
  const int m0 = (wgid / nx) * 128, n0 = (wgid % nx) * 128;

  f32x4 acc[4][4];
  const f32x4 z4 = {0.f, 0.f, 0.f, 0.f};
#pragma unroll
  for (int i = 0; i < 4; ++i)
#pragma unroll
    for (int j = 0; j < 4; ++j) acc[i][j] = z4;

  auto stage = [&](int b, int k0) {
#pragma unroll
    for (int i = 0; i < 4; ++i) {
      const int cb = i * 256 + wave * 64;
      const int c = cb + lane;
      const int row = c >> 3;
      const int sc = ((c & 7) ^ (row & 7)) * 8;
      gload_lds16(A + (size_t)(m0 + row) * ldk + k0 + sc, &Als[b][cb * 8]);
      gload_lds16(Bt + (size_t)(n0 + row) * ldk + k0 + sc, &Bls[b][cb * 8]);
    }
  };

  const int NT = Kc >> 6;
  stage(0, 0);
  if (NT > 1) stage(1, 64);           // 16 loads in flight (tiles 0,1)
  for (int kt = 0; kt < NT; ++kt) {
    const int cur = kt & 1;
    if (kt + 1 < NT)
      asm volatile("s_waitcnt vmcnt(8)" ::: "memory");  // tile kt landed
    else
      asm volatile("s_waitcnt vmcnt(0)" ::: "memory");  // last: drain all
    __builtin_amdgcn_s_barrier();     // B1: tile kt visible to all waves
    __builtin_amdgcn_sched_barrier(0);

    const int sw = r16 & 7;
    bf16x8 af[2][4], bfr[2][4];
#pragma unroll
    for (int ks = 0; ks < 2; ++ks) {
#pragma unroll
      for (int mt = 0; mt < 4; ++mt)
        af[ks][mt] = *(const bf16x8*)&Als[cur][(wm * 64 + mt * 16 + r16) * 64 +
                                              (((ks << 2) | g) ^ sw) * 8];
#pragma unroll
      for (int nt = 0; nt < 4; ++nt)
        bfr[ks][nt] = *(const bf16x8*)&Bls[cur][(wn * 64 + nt * 16 + r16) * 64 +
                                               (((ks << 2) | g) ^ sw) * 8];
    }
    asm volatile("s_waitcnt lgkmcnt(0)" ::: "memory");
    __builtin_amdgcn_sched_barrier(0);
    __builtin_amdgcn_s_barrier();     // B2: all waves' reads of buf[cur] done
    if (kt + 2 < NT) stage(cur, (kt + 2) << 6);  // overwrite in MFMA shadow

    __builtin_amdgcn_s_setprio(1);
#pragma unroll
    for (int ks = 0; ks < 2; ++ks)
#pragma unroll
      for (int mt = 0; mt < 4; ++mt)
#pragma unroll
        for (int nt = 0; nt < 4; ++nt)
          acc[mt][nt] = __builtin_amdgcn_mfma_f32_16x16x32_bf16(
              af[ks][mt], bfr[ks][nt], acc[mt][nt], 0, 0, 0);
    __builtin_amdgcn_s_setprio(0);
  }
#pragma unroll
  for (int mt = 0; mt < 4; ++mt)
#pragma unroll
    for (int nt = 0; nt < 4; ++nt)
#pragma unroll
      for (int r = 0; r < 4; ++r)
        epilogue_elem<EPI>(acc[mt][nt][r], m0 + wm * 64 + mt * 16 + g * 4 + r,
                           n0 + wn * 64 + nt * 16 + r16, N, ep);
}

// ---------------------------------------------------------------------------
// Flash attention (R10 form): swapped-operand 32x32x16, frag-stream I/O,
// K dbuf, XCD grouping, in-register softmax, exp2 domain, native v_exp.
// ---------------------------------------------------------------------------
struct AttnState {
  f32x16 o0, o1;
  float m, lsum;
};

DEV void load_k(const unsigned short* kbase, int s, bf16x8 k0[4], bf16x8 k1[4]) {
  const unsigned short* p = kbase + (size_t)(s >> 5) * 2048;
#pragma unroll
  for (int kk = 0; kk < 4; ++kk) {
    k0[kk] = *(const bf16x8*)(p + kk * 512);
    k1[kk] = *(const bf16x8*)(p + 2048 + kk * 512);
  }
}

DEV void attn_tile(const bf16x8 k0[4], const bf16x8 k1[4],
                   const bf16x8 v0[4], const bf16x8 v1[4],
                   const bf16x8 qf[4], AttnState& st) {
  const f32x16 z16 = {0.f};
  f32x16 pA = z16, pB = z16;
  __builtin_amdgcn_s_setprio(1);
#pragma unroll
  for (int kk = 0; kk < 4; ++kk) {
    pA = __builtin_amdgcn_mfma_f32_32x32x16_bf16(k0[kk], qf[kk], pA, 0, 0, 0);
    pB = __builtin_amdgcn_mfma_f32_32x32x16_bf16(k1[kk], qf[kk], pB, 0, 0, 0);
  }
  __builtin_amdgcn_s_setprio(0);
  float m0 = fmaxf(pA[0], pB[0]), m1 = fmaxf(pA[1], pB[1]);
  float m2 = fmaxf(pA[2], pB[2]), m3 = fmaxf(pA[3], pB[3]);
#pragma unroll
  for (int r = 4; r < 16; r += 4) {
    m0 = fmaxf(m0, fmaxf(pA[r + 0], pB[r + 0]));
    m1 = fmaxf(m1, fmaxf(pA[r + 1], pB[r + 1]));
    m2 = fmaxf(m2, fmaxf(pA[r + 2], pB[r + 2]));
    m3 = fmaxf(m3, fmaxf(pA[r + 3], pB[r + 3]));
  }
  float mx = fmaxf(fmaxf(m0, m1), fmaxf(m2, m3));
  mx = fmaxf(mx, __shfl_xor(mx, 32));
  if (__any(mx > st.m + 11.5416f)) {  // defer-max, exp2 domain (8*log2e)
    const float mnew = fmaxf(st.m, mx);
    const float corr = __builtin_amdgcn_exp2f(st.m - mnew);
#pragma unroll
    for (int r = 0; r < 16; ++r) { st.o0[r] *= corr; st.o1[r] *= corr; }
    st.lsum *= corr;
    st.m = mnew;
  }
  float ps = 0.f;
#pragma unroll
  for (int r = 0; r < 16; ++r) {
    pA[r] = __builtin_amdgcn_exp2f(pA[r] - st.m); ps += pA[r];
    pB[r] = __builtin_amdgcn_exp2f(pB[r] - st.m); ps += pB[r];
  }
  ps += __shfl_xor(ps, 32);
  st.lsum += ps;
  bf16x8 pw[4];
#pragma unroll
  for (int w = 0; w < 4; ++w) {
    unsigned int wd0, wd1, wd2, wd3;
    const int e0 = (w & 1) * 8;
    if (w < 2) {
      asm("v_cvt_pk_bf16_f32 %0, %1, %2" : "=v"(wd0) : "v"(pA[e0 + 0]), "v"(pA[e0 + 1]));
      asm("v_cvt_pk_bf16_f32 %0, %1, %2" : "=v"(wd1) : "v"(pA[e0 + 2]), "v"(pA[e0 + 3]));
      asm("v_cvt_pk_bf16_f32 %0, %1, %2" : "=v"(wd2) : "v"(pA[e0 + 4]), "v"(pA[e0 + 5]));
      asm("v_cvt_pk_bf16_f32 %0, %1, %2" : "=v"(wd3) : "v"(pA[e0 + 6]), "v"(pA[e0 + 7]));
    } else {
      asm("v_cvt_pk_bf16_f32 %0, %1, %2" : "=v"(wd0) : "v"(pB[e0 + 0]), "v"(pB[e0 + 1]));
      asm("v_cvt_pk_bf16_f32 %0, %1, %2" : "=v"(wd1) : "v"(pB[e0 + 2]), "v"(pB[e0 + 3]));
      asm("v_cvt_pk_bf16_f32 %0, %1, %2" : "=v"(wd2) : "v"(pB[e0 + 4]), "v"(pB[e0 + 5]));
      asm("v_cvt_pk_bf16_f32 %0, %1, %2" : "=v"(wd3) : "v"(pB[e0 + 6]), "v"(pB[e0 + 7]));
    }
    u32x4 wv = {wd0, wd1, wd2, wd3};
    pw[w] = __builtin_bit_cast(bf16x8, wv);
  }
  __builtin_amdgcn_s_setprio(1);
#pragma unroll
  for (int w = 0; w < 4; ++w) {
    st.o0 = __builtin_amdgcn_mfma_f32_32x32x16_bf16(v0[w], pw[w], st.o0, 0, 0, 0);
    st.o1 = __builtin_amdgcn_mfma_f32_32x32x16_bf16(v1[w], pw[w], st.o1, 0, 0, 0);
  }
  __builtin_amdgcn_s_setprio(0);
}

__global__ __launch_bounds__(256, 2) void attn_kernel(
    const unsigned short* __restrict__ Qc, const unsigned short* __restrict__ Kc,
    const unsigned short* __restrict__ Vt, unsigned short* __restrict__ Oc) {
  const int lane = threadIdx.x & 63, wave = threadIdx.x >> 6;
  const int hi = lane >> 5, l31 = lane & 31;
  const int i = blockIdx.x;
  const int k8 = i & 7, mq = i >> 3;
  const int grp = k8 + 8 * (mq >> 4);
  const int qb = mq & 15;
  const int b = grp >> 4, h = grp & 15;
  const int q0 = qb * 128 + wave * 32;

  const unsigned short* qbp = Qc + ((size_t)grp * 64 + (q0 >> 5)) * 2048 + lane * 8;
  const unsigned short* kbp = Kc + (size_t)grp * 64 * 2048 + lane * 8;
  const unsigned short* vbp = Vt + (size_t)grp * 32 * 4096 + lane * 8;

  bf16x8 qf[4];
#pragma unroll
  for (int kk = 0; kk < 4; ++kk) qf[kk] = *(const bf16x8*)(qbp + kk * 512);

  AttnState st;
#pragma unroll
  for (int r = 0; r < 16; ++r) { st.o0[r] = 0.f; st.o1[r] = 0.f; }
  st.m = -1e30f; st.lsum = 0.f;

  bf16x8 kA0[4], kA1[4], kB0[4], kB1[4];
  load_k(kbp, 0, kA0, kA1);

  for (int s0 = 0; s0 < SEQ; s0 += 128) {
    const unsigned short* vt0 = vbp + (size_t)(s0 >> 6) * 4096;
    bf16x8 v0[4], v1[4];
#pragma unroll
    for (int w = 0; w < 4; ++w) {
      v0[w] = *(const bf16x8*)(vt0 + w * 512);
      v1[w] = *(const bf16x8*)(vt0 + 2048 + w * 512);
    }
    load_k(kbp, s0 + 64, kB0, kB1);
    attn_tile(kA0, kA1, v0, v1, qf, st);
    const unsigned short* vt1 = vbp + (size_t)((s0 + 64) >> 6) * 4096;
#pragma unroll
    for (int w = 0; w < 4; ++w) {
      v0[w] = *(const bf16x8*)(vt1 + w * 512);
      v1[w] = *(const bf16x8*)(vt1 + 2048 + w * 512);
    }
    const int snext = (s0 + 128 < SEQ) ? (s0 + 128) : 0;
    load_k(kbp, snext, kA0, kA1);
    attn_tile(kB0, kB1, v0, v1, qf, st);
  }

  const float inv = 1.0f / st.lsum;
  const size_t rowbase = (size_t)b * SEQ;
  unsigned short* op = Oc + (rowbase + q0 + l31) * DM + h * DKH + hi * 4;
#pragma unroll
  for (int dblk = 0; dblk < 2; ++dblk)
#pragma unroll
    for (int g4 = 0; g4 < 4; ++g4) {
      u16x4 stv;
#pragma unroll
      for (int r = 0; r < 4; ++r) {
        const float v = (dblk ? st.o1[g4 * 4 + r] : st.o0[g4 * 4 + r]) * inv;
        stv[r] = f2bf(v);
      }
      *(u16x4*)(op + dblk * 32 + g4 * 8) = stv;
    }
}

// ---------------------------------------------------------------------------
extern "C" void kernel_launch(void* const* d_in, const int* in_sizes, int n_in,
                              void* d_out, int out_size, void* d_ws,
                              size_t ws_size, hipStream_t stream) {
  (void)in_sizes; (void)n_in; (void)out_size; (void)ws_size;
  const float* x   = (const float*)d_in[0];
  const float* Wq  = (const float*)d_in[1];
  const float* Wk  = (const float*)d_in[2];
  const float* Wv  = (const float*)d_in[3];
  const float* Wo  = (const float*)d_in[4];
  const float* W1  = (const float*)d_in[5];
  const float* b1  = (const float*)d_in[6];
  const float* W2  = (const float*)d_in[7];
  const float* b2  = (const float*)d_in[8];
  const float* g1  = (const float*)d_in[9];
  const float* be1 = (const float*)d_in[10];
  const float* g2  = (const float*)d_in[11];
  const float* be2 = (const float*)d_in[12];
  float* out = (float*)d_out;

  char* ws = (char*)d_ws;
  const size_t MB = 1024 * 1024;
  unsigned short* h_buf  = (unsigned short*)(ws + 0 * MB);
  unsigned short* wqkv_t = (unsigned short*)(ws + 8 * MB);
  unsigned short* wo_t   = (unsigned short*)(ws + 14 * MB);
  unsigned short* w1_t   = (unsigned short*)(ws + 16 * MB);
  unsigned short* w2_t   = (unsigned short*)(ws + 24 * MB);
  unsigned short* q_attn = (unsigned short*)(ws + 32 * MB);
  unsigned short* k_attn = (unsigned short*)(ws + 40 * MB);
  unsigned short* v_attn = (unsigned short*)(ws + 48 * MB);
  unsigned short* ffn1   = (unsigned short*)(ws + 32 * MB);  // overlaps q/k/v

  EpiArgs e0 = {}; e0.q = q_attn; e0.k = k_attn; e0.vt = v_attn;
  EpiArgs e1 = {}; e1.of32 = out; e1.resid = x;
  EpiArgs e2 = {}; e2.ob16 = ffn1; e2.bias = b1;
  EpiArgs e5 = {}; e5.of32 = out; e5.bias = b2;

  prep_kernel<<<3072 + NTOK, 256, 0, stream>>>(
      x, g1, be1, h_buf, Wq, Wk, Wv, Wo, W1, W2, wqkv_t, wo_t, w1_t, w2_t);
  gemm_256<0><<<dim3(3072 / 256, NTOK / 256), 512, 0, stream>>>(
      h_buf, wqkv_t, 3072, DM, DM, e0);
  attn_kernel<<<512, 256, 0, stream>>>(q_attn, k_attn, v_attn, h_buf);
  gemm_pipe<1><<<dim3(DM / 128, NTOK / 128), 256, 0, stream>>>(
      h_buf, wo_t, DM, DM, DM, e1);
  ln_kernel<<<NTOK, 256, 0, stream>>>(out, g2, be2, h_buf);
  gemm_256<2><<<dim3(DFF / 256, NTOK / 256), 512, 0, stream>>>(
      h_buf, w1_t, DFF, DM, DM, e2);
  gemm_pipe<5><<<dim3(DM / 128, NTOK / 128), 256, 0, stream>>>(
      ffn1, w2_t, DM, DFF, DFF, e5);
}

// Round 23
// 240.967 us; speedup vs baseline: 1.0283x; 1.0283x over previous
//
#include <hip/hip_runtime.h>
#include <stdint.h>

// ---------------------------------------------------------------------------
// TransformerBlock: pre-LN MHA + pre-LN FFN(GELU), bf16 MFMA internals.
// B=2 S=2048 D=1024 H=16 dk=64 Dff=4096.
// R23 = exact revert to R21 (measured best, 240.6us).  R22's FFN2
// single-pass refuted: at 1 blk/CU (1 wave/SIMD) the deep-lead pipeline
// has no TLP to hide the per-tile vmcnt drain (66.7us, 9.7% occupancy);
// split-K=2's 2 waves/SIMD is worth more than the 64MB partial traffic.
// Config: gemm_256 (R20 4-phase, 2-tile lead) QKV/FFN1; gemm_pipe
// (R21 deep-lead) Wo single-pass + FFN2 split-K=2 + reduce_add;
// attn R10 (58us plateau); prep fusion (transpose+LN1).
// Workspace layout (64 MB):
//   [ 0MB) h_buf [4096,1024]bf16 (h1/attn/h2)   } 0-16MB dead at FFN2 time ->
//   [ 8MB) wqkv_t[3072,1024]bf16                }   p0 fp32 partial (16MB)
//   [14MB) wo_t  [1024,1024]bf16
//   [16MB) w1_t  [4096,1024]bf16
//   [24MB) w2_t  [1024,4096]bf16
//   [32MB) q_attn 8MB / k_attn 8MB / v_attn 8MB } ffn1 [4096,4096] overlaps
// d_out doubles as x2 (attn residual) between the Wo GEMM and FFN2.
// ---------------------------------------------------------------------------

typedef __attribute__((ext_vector_type(8))) short bf16x8;
typedef __attribute__((ext_vector_type(4))) float f32x4;
typedef __attribute__((ext_vector_type(16))) float f32x16;
typedef __attribute__((ext_vector_type(4))) unsigned short u16x4;
typedef __attribute__((ext_vector_type(4))) unsigned int u32x4;

#define DEV __device__ __forceinline__

static constexpr int DM   = 1024;
static constexpr int DFF  = 4096;
static constexpr int NH   = 16;
static constexpr int DKH  = 64;
static constexpr int SEQ  = 2048;
static constexpr int NBAT = 2;
static constexpr int NTOK = NBAT * SEQ;  // 4096

DEV unsigned short f2bf(float f) {
  union { float f; unsigned int u; } v; v.f = f;
  unsigned int u = v.u;
  return (unsigned short)((u + 0x7fffu + ((u >> 16) & 1u)) >> 16);
}

DEV void gload_lds16(const unsigned short* g, unsigned short* l) {
  __builtin_amdgcn_global_load_lds(
      (const __attribute__((address_space(1))) unsigned int*)g,
      (__attribute__((address_space(3))) unsigned int*)l, 16, 0, 0);
}

// A&S 7.1.26 erf (|err| <= 1.5e-7), exact-GELU epilogue helper.
DEV float fast_gelu(float x) {
  const float z = fabsf(x) * 0.70710678118654752f;
  const float t = __builtin_amdgcn_rcpf(1.0f + 0.3275911f * z);
  float p = 1.061405429f;
  p = p * t - 1.453152027f;
  p = p * t + 1.421413741f;
  p = p * t - 0.284496736f;
  p = p * t + 0.254829592f;
  p = p * t;
  float erfv = 1.0f - p * __expf(-z * z);
  erfv = copysignf(erfv, x);
  return 0.5f * x * (1.0f + erfv);
}

// ---------------------------------------------------------------------------
// LayerNorm body: x fp32 [rows,1024] -> bf16 out; one 256-thr block per row.
// ---------------------------------------------------------------------------
DEV void ln_body(const float* __restrict__ x, const float* __restrict__ g,
                 const float* __restrict__ be, unsigned short* __restrict__ out,
                 int row, float* rs_, float* rq_) {
  const int t = threadIdx.x;
  const int lane = t & 63, w = t >> 6;
  const float4* xr = (const float4*)(x + (size_t)row * DM);
  float4 v = xr[t];
  float s  = v.x + v.y + v.z + v.w;
  float s2 = v.x * v.x + v.y * v.y + v.z * v.z + v.w * v.w;
#pragma unroll
  for (int off = 32; off; off >>= 1) {
    s  += __shfl_down(s, off);
    s2 += __shfl_down(s2, off);
  }
  if (lane == 0) { rs_[w] = s; rq_[w] = s2; }
  __syncthreads();
  float fs = rs_[0] + rs_[1] + rs_[2] + rs_[3];
  float fq = rq_[0] + rq_[1] + rq_[2] + rq_[3];
  float mu = fs * (1.0f / DM);
  float var = fq * (1.0f / DM) - mu * mu;
  float rstd = rsqrtf(var + 1e-5f);
  float4 gv = ((const float4*)g)[t];
  float4 bv = ((const float4*)be)[t];
  u16x4 o;
  o[0] = f2bf((v.x - mu) * rstd * gv.x + bv.x);
  o[1] = f2bf((v.y - mu) * rstd * gv.y + bv.y);
  o[2] = f2bf((v.z - mu) * rstd * gv.z + bv.z);
  o[3] = f2bf((v.w - mu) * rstd * gv.w + bv.w);
  *(u16x4*)(out + (size_t)row * DM + t * 4) = o;
}

__global__ __launch_bounds__(256) void ln_kernel(
    const float* __restrict__ x, const float* __restrict__ g,
    const float* __restrict__ be, unsigned short* __restrict__ out) {
  __shared__ float rs_[4], rq_[4];
  ln_body(x, g, be, out, blockIdx.x, rs_, rq_);
}

// ---------------------------------------------------------------------------
// Fused prelude: blocks [0,3072) = weight transpose; [3072,7168) = LN1 rows.
// ---------------------------------------------------------------------------
__global__ __launch_bounds__(256) void prep_kernel(
    const float* __restrict__ x, const float* __restrict__ g1,
    const float* __restrict__ be1, unsigned short* __restrict__ lnout,
    const float* __restrict__ Wq, const float* __restrict__ Wk,
    const float* __restrict__ Wv, const float* __restrict__ Wo,
    const float* __restrict__ W1, const float* __restrict__ W2,
    unsigned short* __restrict__ wqkv_t, unsigned short* __restrict__ wo_t,
    unsigned short* __restrict__ w1_t, unsigned short* __restrict__ w2_t) {
  __shared__ float lds[64][65];
  __shared__ float rs_[4], rq_[4];
  const int t = blockIdx.x;
  if (t >= 3072) {
    ln_body(x, g1, be1, lnout, t - 3072, rs_, rq_);
    return;
  }
  const float* inb; unsigned short* outb; int in_ld, out_ld;
  if (t < 768) {            // wqkv_t[n=which*1024+h*64+kk][d] = W[h][d][kk]
    const int slice = t >> 4, tin = t & 15;
    const int which = slice >> 4, h = slice & 15;
    const float* W = (which == 0) ? Wq : (which == 1) ? Wk : Wv;
    inb = W + (size_t)((h << 10) + (tin << 6)) * 64;
    in_ld = 64;
    outb = wqkv_t + ((size_t)((which << 10) + (h << 6)) << 10) + (tin << 6);
    out_ld = 1024;
  } else if (t < 1024) {    // wo_t[n][d] = Wo[d][n]
    const int tt = t - 768, tr = tt >> 4, tc = tt & 15;
    inb = Wo + (size_t)(tc << 6) * 1024 + (tr << 6); in_ld = 1024;
    outb = wo_t + (size_t)(tr << 6) * 1024 + (tc << 6); out_ld = 1024;
  } else if (t < 2048) {    // w1_t[n(4096)][d] = W1[d][n]
    const int tt = t - 1024, tr = tt >> 4, tc = tt & 15;
    inb = W1 + (size_t)(tc << 6) * 4096 + (tr << 6); in_ld = 4096;
    outb = w1_t + (size_t)(tr << 6) * 1024 + (tc << 6); out_ld = 1024;
  } else {                  // w2_t[n(1024)][s(4096)] = W2[s][n]
    const int tt = t - 2048, tr = tt >> 6, tc = tt & 63;
    inb = W2 + (size_t)(tc << 6) * 1024 + (tr << 6); in_ld = 1024;
    outb = w2_t + (size_t)(tr << 6) * 4096 + (tc << 6); out_ld = 4096;
  }
  const int j = threadIdx.x & 63, i0 = threadIdx.x >> 6;
#pragma unroll
  for (int p = 0; p < 16; ++p) {
    const int i = i0 + p * 4;
    lds[j][i] = inb[(size_t)i * in_ld + j];
  }
  __syncthreads();
#pragma unroll
  for (int p = 0; p < 16; ++p) {
    const int r = i0 + p * 4;
    outb[(size_t)r * out_ld + j] = f2bf(lds[r][j]);
  }
}

// ---------------------------------------------------------------------------
struct EpiArgs {
  unsigned short* q;     // EPI0 (frag-stream)
  unsigned short* k;     // EPI0 (frag-stream)
  unsigned short* vt;    // EPI0 (frag-stream, kv bit2<->3 folded)
  unsigned short* ob16;  // EPI2
  float* of32;           // EPI1 / EPI4(z=1)
  float* p0;             // EPI4(z=0) fp32 partial
  const float* bias;     // EPI2 / EPI4
  const float* resid;    // EPI1
};

template <int EPI>
DEV void epilogue_elem(float v, int row, int col, int N, int bz,
                       const EpiArgs& ep) {
  if constexpr (EPI == 0) {  // QKV -> fragment-stream scratch layouts
    const int bb = row >> 11, rr = row & 2047;
    if (col < 1024) {        // Q (pre-scaled by log2e/sqrt(dk) -> exp2 domain)
      const int hh = col >> 6, dk = col & 63;
      const int kk = dk >> 4, h8 = (dk >> 3) & 1, e = dk & 7;
      const int qblk = rr >> 5, l31 = rr & 31;
      ep.q[((size_t)(bb * NH + hh) * 64 + qblk) * 2048 + kk * 512 +
           (h8 * 32 + l31) * 8 + e] = f2bf(v * 0.18033688011112042f);
    } else if (col < 2048) { // K
      const int c = col - 1024;
      const int hh = c >> 6, dk = c & 63;
      const int kk = dk >> 4, h8 = (dk >> 3) & 1, e = dk & 7;
      const int kvblk = rr >> 5, l31 = rr & 31;
      ep.k[((size_t)(bb * NH + hh) * 64 + kvblk) * 2048 + kk * 512 +
           (h8 * 32 + l31) * 8 + e] = f2bf(v);
    } else {                 // V (kv bit2<->3 swizzle folded in)
      const int c = col - 2048, hh = c >> 6, dd = c & 63;
      const int ssw = (rr & ~12) | ((rr & 4) << 1) | ((rr & 8) >> 1);
      const int t64 = ssw >> 6, w = (ssw >> 4) & 3;
      const int h8 = (ssw >> 3) & 1, e = ssw & 7;
      const int dblk = dd >> 5, l31 = dd & 31;
      ep.vt[(((size_t)(bb * NH + hh) * 32 + t64) * 8 + dblk * 4 + w) * 512 +
            (h8 * 32 + l31) * 8 + e] = f2bf(v);
    }
  } else if constexpr (EPI == 1) {  // Wo: + residual -> fp32 (x2 into d_out)
    const size_t idx = (size_t)row * N + col;
    ep.of32[idx] = v + ep.resid[idx];
  } else if constexpr (EPI == 2) {  // + bias, exact GELU (A&S poly) -> bf16
    ep.ob16[(size_t)row * N + col] = f2bf(fast_gelu(v + ep.bias[col]));
  } else {  // EPI 4: FFN2 split-K. z=0 -> fp32 partial; z=1 -> out += v+bias
    const size_t idx = (size_t)row * N + col;
    if (bz == 0) ep.p0[idx] = v;
    else ep.of32[idx] = ep.of32[idx] + v + ep.bias[col];
  }
}

// ---------------------------------------------------------------------------
// gemm_256 (R20): 256x256 tile, 8 waves, BK=64, 2-tile prefetch lead,
// 4 compute phases (Q0..Q3), tile T's P4 stages tile T+2.
// ---------------------------------------------------------------------------
template <int EPI>
__global__ __launch_bounds__(512, 2) void gemm_256(
    const unsigned short* __restrict__ A, const unsigned short* __restrict__ Bt,
    int N, int K, int ldk, EpiArgs ep) {
  __shared__ __align__(16) unsigned short Als[2][256 * 64];
  __shared__ __align__(16) unsigned short Bls[2][256 * 64];
  const int t = threadIdx.x, lane = t & 63, wave = t >> 6;
  const int wm = wave >> 2, wn = wave & 3;
  const int g = lane >> 4, r16 = lane & 15;
  const int nx = gridDim.x, nwg = nx * gridDim.y;
  int wgid = blockIdx.y * nx + blockIdx.x;
  wgid = (wgid & 7) * (nwg >> 3) + (wgid >> 3);
  const int m0 = (wgid / nx) * 256, n0 = (wgid % nx) * 256;

  f32x4 acc[8][4];
  const f32x4 z4 = {0.f, 0.f, 0.f, 0.f};
#pragma unroll
  for (int i = 0; i < 8; ++i)
#pragma unroll
    for (int j = 0; j < 4; ++j) acc[i][j] = z4;

  auto stage_half = [&](int b, int k0, int h) {
#pragma unroll
    for (int i = 0; i < 2; ++i) {
      const int c = i * 512 + t;
      const int row = c >> 3;
      const int sc = ((c & 7) ^ (row & 7)) * 8;
      const int dofs = ((h & 1) << 13) + (i * 512 + (wave << 6)) * 8;
      if (h < 2)
        gload_lds16(A + (size_t)(m0 + ((h & 1) << 7) + row) * ldk + k0 + sc,
                    &Als[b][dofs]);
      else
        gload_lds16(Bt + (size_t)(n0 + ((h & 1) << 7) + row) * ldk + k0 + sc,
                    &Bls[b][dofs]);
    }
  };
  auto stage_tile = [&](int b, int k0) {
#pragma unroll
    for (int h = 0; h < 4; ++h) stage_half(b, k0, h);
  };

  const int NT = K >> 6;
  stage_tile(0, 0);
  if (NT > 1) {
    stage_tile(1, 64);
    asm volatile("s_waitcnt vmcnt(8)" ::: "memory");
  } else {
    asm volatile("s_waitcnt vmcnt(0)" ::: "memory");
  }
  __builtin_amdgcn_s_barrier();

  bf16x8 Af[4][2], Bl[2][2], Bh[2][2];
  for (int T = 0; T < NT; ++T) {
    const int cur = T & 1;
    // ---- P1: ds_read A-low + B-low; MFMA Q0 ----
#pragma unroll
    for (int mf = 0; mf < 4; ++mf) {
      const int row = (wm << 7) + (mf << 4) + r16;
#pragma unroll
      for (int ks = 0; ks < 2; ++ks)
        Af[mf][ks] = *(const bf16x8*)
            &Als[cur][row * 64 + ((((ks << 2) | g) ^ (row & 7)) << 3)];
    }
#pragma unroll
    for (int ni = 0; ni < 2; ++ni) {
      const int row = (wn << 6) + (ni << 4) + r16;
#pragma unroll
      for (int ks = 0; ks < 2; ++ks)
        Bl[ni][ks] = *(const bf16x8*)
            &Bls[cur][row * 64 + ((((ks << 2) | g) ^ (row & 7)) << 3)];
    }
    asm volatile("s_waitcnt lgkmcnt(0)" ::: "memory");
    __builtin_amdgcn_sched_barrier(0);
    __builtin_amdgcn_s_setprio(1);
#pragma unroll
    for (int ks = 0; ks < 2; ++ks)
#pragma unroll
      for (int mf = 0; mf < 4; ++mf)
#pragma unroll
        for (int ni = 0; ni < 2; ++ni)
          acc[mf][ni] = __builtin_amdgcn_mfma_f32_16x16x32_bf16(
              Af[mf][ks], Bl[ni][ks], acc[mf][ni], 0, 0, 0);
    __builtin_amdgcn_s_setprio(0);
    __builtin_amdgcn_s_barrier();
    // ---- P2: ds_read B-high; MFMA Q1 ----
#pragma unroll
    for (int ni = 0; ni < 2; ++ni) {
      const int row = (wn << 6) + ((2 + ni) << 4) + r16;
#pragma unroll
      for (int ks = 0; ks < 2; ++ks)
        Bh[ni][ks] = *(const bf16x8*)
            &Bls[cur][row * 64 + ((((ks << 2) | g) ^ (row & 7)) << 3)];
    }
    asm volatile("s_waitcnt lgkmcnt(0)" ::: "memory");
    __builtin_amdgcn_sched_barrier(0);
    __builtin_amdgcn_s_setprio(1);
#pragma unroll
    for (int ks = 0; ks < 2; ++ks)
#pragma unroll
      for (int mf = 0; mf < 4; ++mf)
#pragma unroll
        for (int ni = 0; ni < 2; ++ni)
          acc[mf][2 + ni] = __builtin_amdgcn_mfma_f32_16x16x32_bf16(
              Af[mf][ks], Bh[ni][ks], acc[mf][2 + ni], 0, 0, 0);
    __builtin_amdgcn_s_setprio(0);
    __builtin_amdgcn_s_barrier();
    // ---- P3: ds_read A-high (overwrites Af); MFMA Q2 ----
#pragma unroll
    for (int mf = 0; mf < 4; ++mf) {
      const int row = (wm << 7) + ((4 + mf) << 4) + r16;
#pragma unroll
      for (int ks = 0; ks < 2; ++ks)
        Af[mf][ks] = *(const bf16x8*)
            &Als[cur][row * 64 + ((((ks << 2) | g) ^ (row & 7)) << 3)];
    }
    asm volatile("s_waitcnt lgkmcnt(0)" ::: "memory");
    __builtin_amdgcn_sched_barrier(0);
    __builtin_amdgcn_s_setprio(1);
#pragma unroll
    for (int ks = 0; ks < 2; ++ks)
#pragma unroll
      for (int mf = 0; mf < 4; ++mf)
#pragma unroll
        for (int ni = 0; ni < 2; ++ni)
          acc[4 + mf][ni] = __builtin_amdgcn_mfma_f32_16x16x32_bf16(
              Af[mf][ks], Bl[ni][ks], acc[4 + mf][ni], 0, 0, 0);
    __builtin_amdgcn_s_setprio(0);
    __builtin_amdgcn_s_barrier();
    // ---- P4: issue tile T+2 (into T's buffer); MFMA Q3 ----
    if (T + 2 < NT) stage_tile(cur, (T + 2) << 6);
    __builtin_amdgcn_s_setprio(1);
#pragma unroll
    for (int ks = 0; ks < 2; ++ks)
#pragma unroll
      for (int mf = 0; mf < 4; ++mf)
#pragma unroll
        for (int ni = 0; ni < 2; ++ni)
          acc[4 + mf][2 + ni] = __builtin_amdgcn_mfma_f32_16x16x32_bf16(
              Af[mf][ks], Bh[ni][ks], acc[4 + mf][2 + ni], 0, 0, 0);
    __builtin_amdgcn_s_setprio(0);
    if (T + 1 < NT)
      asm volatile("s_waitcnt vmcnt(8)" ::: "memory");
    __builtin_amdgcn_s_barrier();
  }
#pragma unroll
  for (int mf = 0; mf < 8; ++mf)
#pragma unroll
    for (int nf = 0; nf < 4; ++nf)
#pragma unroll
      for (int r = 0; r < 4; ++r)
        epilogue_elem<EPI>(acc[mf][nf][r],
                           m0 + (wm << 7) + (mf << 4) + (g << 2) + r,
                           n0 + (wn << 6) + (nf << 4) + r16, N, 0, ep);
}

// ---------------------------------------------------------------------------
// Pipelined GEMM (128^2 tile, BK=64, LDS dbuf) -- Wo (single) / FFN2 (z=2).
// R21 deep lead: prologue stages tiles 0,1.  Per tile: vmcnt(8|0) ->
// B1 -> ds_read x16 -> lgkmcnt(0) -> B2 (reads done) -> stage(T+2 into
// buf[cur]) -> 32 MFMA (monolithic).
// ---------------------------------------------------------------------------
template <int EPI>
__global__ __launch_bounds__(256) void gemm_pipe(
    const unsigned short* __restrict__ A, const unsigned short* __restrict__ Bt,
    int N, int Kc, int ldk, EpiArgs ep) {
  __shared__ __align__(16) unsigned short Als[2][128 * 64];
  __shared__ __align__(16) unsigned short Bls[2][128 * 64];
  const int t = threadIdx.x, lane = t & 63, wave = t >> 6;
  const int wm = wave >> 1, wn = wave & 1;
  const int g = lane >> 4, r16 = lane & 15;
  const int nx = gridDim.x;
  const int nwg = nx * gridDim.y;
  int wgid = blockIdx.y * nx + blockIdx.x;
  wgid = (wgid & 7) * (nwg >> 3) + (wgid >> 3);
  const int m0 = (wgid / nx) * 128, n0 = (wgid % nx) * 128;
  const int kbase = blockIdx.z * Kc;

  f32x4 acc[4][4];
  const f32x4 z4 = {0.f, 0.f, 0.f, 0.f};
#pragma unroll
  for (int i = 0; i < 4; ++i)
#pragma unroll
    for (int j = 0; j < 4; ++j) acc[i][j] = z4;

  auto stage = [&](int b, int k0) {
#pragma unroll
    for (int i = 0; i < 4; ++i) {
      const int cb = i * 256 + wave * 64;
      const int c = cb + lane;
      const int row = c >> 3;
      const int sc = ((c & 7) ^ (row & 7)) * 8;
      gload_lds16(A + (size_t)(m0 + row) * ldk + kbase + k0 + sc, &Als[b][cb * 8]);
      gload_lds16(Bt + (size_t)(n0 + row) * ldk + kbase + k0 + sc, &Bls[b][cb * 8]);
    }
  };

  const int NT = Kc >> 6;
  stage(0, 0);
  if (NT > 1) stage(1, 64);           // 16 loads in flight (tiles 0,1)
  for (int kt = 0; kt < NT; ++kt) {
    const int cur = kt & 1;
    if (kt + 1 < NT)
      asm volatile("s_waitcnt vmcnt(8)" ::: "memory");  // tile kt landed
    else
      asm volatile("s_waitcnt vmcnt(0)" ::: "memory");  // last: drain all
    __builtin_amdgcn_s_barrier();     // B1: tile kt visible to all waves
    __builtin_amdgcn_sched_barrier(0);

    const int sw = r16 & 7;
    bf16x8 af[2][4], bfr[2][4];
#pragma unroll
    for (int ks = 0; ks < 2; ++ks) {
#pragma unroll
      for (int mt = 0; mt < 4; ++mt)
        af[ks][mt] = *(const bf16x8*)&Als[cur][(wm * 64 + mt * 16 + r16) * 64 +
                                              (((ks << 2) | g) ^ sw) * 8];
#pragma unroll
      for (int nt = 0; nt < 4; ++nt)
        bfr[ks][nt] = *(const bf16x8*)&Bls[cur][(wn * 64 + nt * 16 + r16) * 64 +
                                               (((ks << 2) | g) ^ sw) * 8];
    }
    asm volatile("s_waitcnt lgkmcnt(0)" ::: "memory");
    __builtin_amdgcn_sched_barrier(0);
    __builtin_amdgcn_s_barrier();     // B2: all waves' reads of buf[cur] done
    if (kt + 2 < NT) stage(cur, (kt + 2) << 6);  // overwrite in MFMA shadow

    __builtin_amdgcn_s_setprio(1);
#pragma unroll
    for (int ks = 0; ks < 2; ++ks)
#pragma unroll
      for (int mt = 0; mt < 4; ++mt)
#pragma unroll
        for (int nt = 0; nt < 4; ++nt)
          acc[mt][nt] = __builtin_amdgcn_mfma_f32_16x16x32_bf16(
              af[ks][mt], bfr[ks][nt], acc[mt][nt], 0, 0, 0);
    __builtin_amdgcn_s_setprio(0);
  }
#pragma unroll
  for (int mt = 0; mt < 4; ++mt)
#pragma unroll
    for (int nt = 0; nt < 4; ++nt)
#pragma unroll
      for (int r = 0; r < 4; ++r)
        epilogue_elem<EPI>(acc[mt][nt][r], m0 + wm * 64 + mt * 16 + g * 4 + r,
                           n0 + wn * 64 + nt * 16 + r16, N, blockIdx.z, ep);
}

// ---------------------------------------------------------------------------
__global__ __launch_bounds__(256) void reduce_add(const float* __restrict__ p,
                                                  float* __restrict__ out) {
  const int i = blockIdx.x * 256 + threadIdx.x;
  float4 a = ((const float4*)p)[i];
  float4 b = ((float4*)out)[i];
  b.x += a.x; b.y += a.y; b.z += a.z; b.w += a.w;
  ((float4*)out)[i] = b;
}

// ---------------------------------------------------------------------------
// Flash attention (R10 form): swapped-operand 32x32x16, frag-stream I/O,
// K dbuf, XCD grouping, in-register softmax, exp2 domain, native v_exp.
// ---------------------------------------------------------------------------
struct AttnState {
  f32x16 o0, o1;
  float m, lsum;
};

DEV void load_k(const unsigned short* kbase, int s, bf16x8 k0[4], bf16x8 k1[4]) {
  const unsigned short* p = kbase + (size_t)(s >> 5) * 2048;
#pragma unroll
  for (int kk = 0; kk < 4; ++kk) {
    k0[kk] = *(const bf16x8*)(p + kk * 512);
    k1[kk] = *(const bf16x8*)(p + 2048 + kk * 512);
  }
}

DEV void attn_tile(const bf16x8 k0[4], const bf16x8 k1[4],
                   const bf16x8 v0[4], const bf16x8 v1[4],
                   const bf16x8 qf[4], AttnState& st) {
  const f32x16 z16 = {0.f};
  f32x16 pA = z16, pB = z16;
  __builtin_amdgcn_s_setprio(1);
#pragma unroll
  for (int kk = 0; kk < 4; ++kk) {
    pA = __builtin_amdgcn_mfma_f32_32x32x16_bf16(k0[kk], qf[kk], pA, 0, 0, 0);
    pB = __builtin_amdgcn_mfma_f32_32x32x16_bf16(k1[kk], qf[kk], pB, 0, 0, 0);
  }
  __builtin_amdgcn_s_setprio(0);
  float m0 = fmaxf(pA[0], pB[0]), m1 = fmaxf(pA[1], pB[1]);
  float m2 = fmaxf(pA[2], pB[2]), m3 = fmaxf(pA[3], pB[3]);
#pragma unroll
  for (int r = 4; r < 16; r += 4) {
    m0 = fmaxf(m0, fmaxf(pA[r + 0], pB[r + 0]));
    m1 = fmaxf(m1, fmaxf(pA[r + 1], pB[r + 1]));
    m2 = fmaxf(m2, fmaxf(pA[r + 2], pB[r + 2]));
    m3 = fmaxf(m3, fmaxf(pA[r + 3], pB[r + 3]));
  }
  float mx = fmaxf(fmaxf(m0, m1), fmaxf(m2, m3));
  mx = fmaxf(mx, __shfl_xor(mx, 32));
  if (__any(mx > st.m + 11.5416f)) {  // defer-max, exp2 domain (8*log2e)
    const float mnew = fmaxf(st.m, mx);
    const float corr = __builtin_amdgcn_exp2f(st.m - mnew);
#pragma unroll
    for (int r = 0; r < 16; ++r) { st.o0[r] *= corr; st.o1[r] *= corr; }
    st.lsum *= corr;
    st.m = mnew;
  }
  float ps = 0.f;
#pragma unroll
  for (int r = 0; r < 16; ++r) {
    pA[r] = __builtin_amdgcn_exp2f(pA[r] - st.m); ps += pA[r];
    pB[r] = __builtin_amdgcn_exp2f(pB[r] - st.m); ps += pB[r];
  }
  ps += __shfl_xor(ps, 32);
  st.lsum += ps;
  bf16x8 pw[4];
#pragma unroll
  for (int w = 0; w < 4; ++w) {
    unsigned int wd0, wd1, wd2, wd3;
    const int e0 = (w & 1) * 8;
    if (w < 2) {
      asm("v_cvt_pk_bf16_f32 %0, %1, %2" : "=v"(wd0) : "v"(pA[e0 + 0]), "v"(pA[e0 + 1]));
      asm("v_cvt_pk_bf16_f32 %0, %1, %2" : "=v"(wd1) : "v"(pA[e0 + 2]), "v"(pA[e0 + 3]));
      asm("v_cvt_pk_bf16_f32 %0, %1, %2" : "=v"(wd2) : "v"(pA[e0 + 4]), "v"(pA[e0 + 5]));
      asm("v_cvt_pk_bf16_f32 %0, %1, %2" : "=v"(wd3) : "v"(pA[e0 + 6]), "v"(pA[e0 + 7]));
    } else {
      asm("v_cvt_pk_bf16_f32 %0, %1, %2" : "=v"(wd0) : "v"(pB[e0 + 0]), "v"(pB[e0 + 1]));
      asm("v_cvt_pk_bf16_f32 %0, %1, %2" : "=v"(wd1) : "v"(pB[e0 + 2]), "v"(pB[e0 + 3]));
      asm("v_cvt_pk_bf16_f32 %0, %1, %2" : "=v"(wd2) : "v"(pB[e0 + 4]), "v"(pB[e0 + 5]));
      asm("v_cvt_pk_bf16_f32 %0, %1, %2" : "=v"(wd3) : "v"(pB[e0 + 6]), "v"(pB[e0 + 7]));
    }
    u32x4 wv = {wd0, wd1, wd2, wd3};
    pw[w] = __builtin_bit_cast(bf16x8, wv);
  }
  __builtin_amdgcn_s_setprio(1);
#pragma unroll
  for (int w = 0; w < 4; ++w) {
    st.o0 = __builtin_amdgcn_mfma_f32_32x32x16_bf16(v0[w], pw[w], st.o0, 0, 0, 0);
    st.o1 = __builtin_amdgcn_mfma_f32_32x32x16_bf16(v1[w], pw[w], st.o1, 0, 0, 0);
  }
  __builtin_amdgcn_s_setprio(0);
}

__global__ __launch_bounds__(256, 2) void attn_kernel(
    const unsigned short* __restrict__ Qc, const unsigned short* __restrict__ Kc,
    const unsigned short* __restrict__ Vt, unsigned short* __restrict__ Oc) {
  const int lane = threadIdx.x & 63, wave = threadIdx.x >> 6;
  const int hi = lane >> 5, l31 = lane & 31;
  const int i = blockIdx.x;
  const int k8 = i & 7, mq = i >> 3;
  const int grp = k8 + 8 * (mq >> 4);
  const int qb = mq & 15;
  const int b = grp >> 4, h = grp & 15;
  const int q0 = qb * 128 + wave * 32;

  const unsigned short* qbp = Qc + ((size_t)grp * 64 + (q0 >> 5)) * 2048 + lane * 8;
  const unsigned short* kbp = Kc + (size_t)grp * 64 * 2048 + lane * 8;
  const unsigned short* vbp = Vt + (size_t)grp * 32 * 4096 + lane * 8;

  bf16x8 qf[4];
#pragma unroll
  for (int kk = 0; kk < 4; ++kk) qf[kk] = *(const bf16x8*)(qbp + kk * 512);

  AttnState st;
#pragma unroll
  for (int r = 0; r < 16; ++r) { st.o0[r] = 0.f; st.o1[r] = 0.f; }
  st.m = -1e30f; st.lsum = 0.f;

  bf16x8 kA0[4], kA1[4], kB0[4], kB1[4];
  load_k(kbp, 0, kA0, kA1);

  for (int s0 = 0; s0 < SEQ; s0 += 128) {
    const unsigned short* vt0 = vbp + (size_t)(s0 >> 6) * 4096;
    bf16x8 v0[4], v1[4];
#pragma unroll
    for (int w = 0; w < 4; ++w) {
      v0[w] = *(const bf16x8*)(vt0 + w * 512);
      v1[w] = *(const bf16x8*)(vt0 + 2048 + w * 512);
    }
    load_k(kbp, s0 + 64, kB0, kB1);
    attn_tile(kA0, kA1, v0, v1, qf, st);
    const unsigned short* vt1 = vbp + (size_t)((s0 + 64) >> 6) * 4096;
#pragma unroll
    for (int w = 0; w < 4; ++w) {
      v0[w] = *(const bf16x8*)(vt1 + w * 512);
      v1[w] = *(const bf16x8*)(vt1 + 2048 + w * 512);
    }
    const int snext = (s0 + 128 < SEQ) ? (s0 + 128) : 0;
    load_k(kbp, snext, kA0, kA1);
    attn_tile(kB0, kB1, v0, v1, qf, st);
  }

  const float inv = 1.0f / st.lsum;
  const size_t rowbase = (size_t)b * SEQ;
  unsigned short* op = Oc + (rowbase + q0 + l31) * DM + h * DKH + hi * 4;
#pragma unroll
  for (int dblk = 0; dblk < 2; ++dblk)
#pragma unroll
    for (int g4 = 0; g4 < 4; ++g4) {
      u16x4 stv;
#pragma unroll
      for (int r = 0; r < 4; ++r) {
        const float v = (dblk ? st.o1[g4 * 4 + r] : st.o0[g4 * 4 + r]) * inv;
        stv[r] = f2bf(v);
      }
      *(u16x4*)(op + dblk * 32 + g4 * 8) = stv;
    }
}

// ---------------------------------------------------------------------------
extern "C" void kernel_launch(void* const* d_in, const int* in_sizes, int n_in,
                              void* d_out, int out_size, void* d_ws,
                              size_t ws_size, hipStream_t stream) {
  (void)in_sizes; (void)n_in; (void)out_size; (void)ws_size;
  const float* x   = (const float*)d_in[0];
  const float* Wq  = (const float*)d_in[1];
  const float* Wk  = (const float*)d_in[2];
  const float* Wv  = (const float*)d_in[3];
  const float* Wo  = (const float*)d_in[4];
  const float* W1  = (const float*)d_in[5];
  const float* b1  = (const float*)d_in[6];
  const float* W2  = (const float*)d_in[7];
  const float* b2  = (const float*)d_in[8];
  const float* g1  = (const float*)d_in[9];
  const float* be1 = (const float*)d_in[10];
  const float* g2  = (const float*)d_in[11];
  const float* be2 = (const float*)d_in[12];
  float* out = (float*)d_out;

  char* ws = (char*)d_ws;
  const size_t MB = 1024 * 1024;
  unsigned short* h_buf  = (unsigned short*)(ws + 0 * MB);
  unsigned short* wqkv_t = (unsigned short*)(ws + 8 * MB);
  unsigned short* wo_t   = (unsigned short*)(ws + 14 * MB);
  unsigned short* w1_t   = (unsigned short*)(ws + 16 * MB);
  unsigned short* w2_t   = (unsigned short*)(ws + 24 * MB);
  unsigned short* q_attn = (unsigned short*)(ws + 32 * MB);
  unsigned short* k_attn = (unsigned short*)(ws + 40 * MB);
  unsigned short* v_attn = (unsigned short*)(ws + 48 * MB);
  unsigned short* ffn1   = (unsigned short*)(ws + 32 * MB);  // overlaps q/k/v
  float*          p0     = (float*)(ws + 0 * MB);  // 16MB; dead bufs @FFN2

  EpiArgs e0 = {}; e0.q = q_attn; e0.k = k_attn; e0.vt = v_attn;
  EpiArgs e1 = {}; e1.of32 = out; e1.resid = x;
  EpiArgs e2 = {}; e2.ob16 = ffn1; e2.bias = b1;
  EpiArgs e4 = {}; e4.of32 = out; e4.p0 = p0; e4.bias = b2;

  prep_kernel<<<3072 + NTOK, 256, 0, stream>>>(
      x, g1, be1, h_buf, Wq, Wk, Wv, Wo, W1, W2, wqkv_t, wo_t, w1_t, w2_t);
  gemm_256<0><<<dim3(3072 / 256, NTOK / 256), 512, 0, stream>>>(
      h_buf, wqkv_t, 3072, DM, DM, e0);
  attn_kernel<<<512, 256, 0, stream>>>(q_attn, k_attn, v_attn, h_buf);
  gemm_pipe<1><<<dim3(DM / 128, NTOK / 128, 1), 256, 0, stream>>>(
      h_buf, wo_t, DM, DM, DM, e1);
  ln_kernel<<<NTOK, 256, 0, stream>>>(out, g2, be2, h_buf);
  gemm_256<2><<<dim3(DFF / 256, NTOK / 256), 512, 0, stream>>>(
      h_buf, w1_t, DFF, DM, DM, e2);
  gemm_pipe<4><<<dim3(DM / 128, NTOK / 128, 2), 256, 0, stream>>>(
      ffn1, w2_t, DM, DFF / 2, DFF, e4);
  reduce_add<<<4096, 256, 0, stream>>>(p0, out);
}

// Round 24
// 240.049 us; speedup vs baseline: 1.0323x; 1.0038x over previous
//
#include <hip/hip_runtime.h>
#include <stdint.h>

// ---------------------------------------------------------------------------
// TransformerBlock: pre-LN MHA + pre-LN FFN(GELU), bf16 MFMA internals.
// B=2 S=2048 D=1024 H=16 dk=64 Dff=4096.
// R24 = R23 (best, 241.0us) + LDS-staged K/V attention: each wave was
// privately reading its (b,h)'s full 512KB K+V from L2 (~1GB total = ~30us
// of the 58us).  The block's 4 waves share K/V -> stage each 64-kv tile
// (8KB K + 8KB V, contiguous in the frag-stream layout) into double-
// buffered LDS via global_load_lds using the R21 deep-lead schedule
// (vmcnt(4|0) -> B1 -> ds_read x16 -> lgkmcnt(0) -> B2 -> stage t+2 ->
// compute).  L2 traffic /4 (~256MB); compute + layouts byte-identical.
// GEMM schedules unchanged: gemm_256 (R20) QKV/FFN1; gemm_pipe (R21)
// Wo single-pass + FFN2 split-K=2 + reduce_add; prep fusion.
// Workspace layout (64 MB):
//   [ 0MB) h_buf [4096,1024]bf16 (h1/attn/h2)   } 0-16MB dead at FFN2 time ->
//   [ 8MB) wqkv_t[3072,1024]bf16                }   p0 fp32 partial (16MB)
//   [14MB) wo_t  [1024,1024]bf16
//   [16MB) w1_t  [4096,1024]bf16
//   [24MB) w2_t  [1024,4096]bf16
//   [32MB) q_attn 8MB / k_attn 8MB / v_attn 8MB } ffn1 [4096,4096] overlaps
// d_out doubles as x2 (attn residual) between the Wo GEMM and FFN2.
// ---------------------------------------------------------------------------

typedef __attribute__((ext_vector_type(8))) short bf16x8;
typedef __attribute__((ext_vector_type(4))) float f32x4;
typedef __attribute__((ext_vector_type(16))) float f32x16;
typedef __attribute__((ext_vector_type(4))) unsigned short u16x4;
typedef __attribute__((ext_vector_type(4))) unsigned int u32x4;

#define DEV __device__ __forceinline__

static constexpr int DM   = 1024;
static constexpr int DFF  = 4096;
static constexpr int NH   = 16;
static constexpr int DKH  = 64;
static constexpr int SEQ  = 2048;
static constexpr int NBAT = 2;
static constexpr int NTOK = NBAT * SEQ;  // 4096

DEV unsigned short f2bf(float f) {
  union { float f; unsigned int u; } v; v.f = f;
  unsigned int u = v.u;
  return (unsigned short)((u + 0x7fffu + ((u >> 16) & 1u)) >> 16);
}

DEV void gload_lds16(const unsigned short* g, unsigned short* l) {
  __builtin_amdgcn_global_load_lds(
      (const __attribute__((address_space(1))) unsigned int*)g,
      (__attribute__((address_space(3))) unsigned int*)l, 16, 0, 0);
}

// A&S 7.1.26 erf (|err| <= 1.5e-7), exact-GELU epilogue helper.
DEV float fast_gelu(float x) {
  const float z = fabsf(x) * 0.70710678118654752f;
  const float t = __builtin_amdgcn_rcpf(1.0f + 0.3275911f * z);
  float p = 1.061405429f;
  p = p * t - 1.453152027f;
  p = p * t + 1.421413741f;
  p = p * t - 0.284496736f;
  p = p * t + 0.254829592f;
  p = p * t;
  float erfv = 1.0f - p * __expf(-z * z);
  erfv = copysignf(erfv, x);
  return 0.5f * x * (1.0f + erfv);
}

// ---------------------------------------------------------------------------
// LayerNorm body: x fp32 [rows,1024] -> bf16 out; one 256-thr block per row.
// ---------------------------------------------------------------------------
DEV void ln_body(const float* __restrict__ x, const float* __restrict__ g,
                 const float* __restrict__ be, unsigned short* __restrict__ out,
                 int row, float* rs_, float* rq_) {
  const int t = threadIdx.x;
  const int lane = t & 63, w = t >> 6;
  const float4* xr = (const float4*)(x + (size_t)row * DM);
  float4 v = xr[t];
  float s  = v.x + v.y + v.z + v.w;
  float s2 = v.x * v.x + v.y * v.y + v.z * v.z + v.w * v.w;
#pragma unroll
  for (int off = 32; off; off >>= 1) {
    s  += __shfl_down(s, off);
    s2 += __shfl_down(s2, off);
  }
  if (lane == 0) { rs_[w] = s; rq_[w] = s2; }
  __syncthreads();
  float fs = rs_[0] + rs_[1] + rs_[2] + rs_[3];
  float fq = rq_[0] + rq_[1] + rq_[2] + rq_[3];
  float mu = fs * (1.0f / DM);
  float var = fq * (1.0f / DM) - mu * mu;
  float rstd = rsqrtf(var + 1e-5f);
  float4 gv = ((const float4*)g)[t];
  float4 bv = ((const float4*)be)[t];
  u16x4 o;
  o[0] = f2bf((v.x - mu) * rstd * gv.x + bv.x);
  o[1] = f2bf((v.y - mu) * rstd * gv.y + bv.y);
  o[2] = f2bf((v.z - mu) * rstd * gv.z + bv.z);
  o[3] = f2bf((v.w - mu) * rstd * gv.w + bv.w);
  *(u16x4*)(out + (size_t)row * DM + t * 4) = o;
}

__global__ __launch_bounds__(256) void ln_kernel(
    const float* __restrict__ x, const float* __restrict__ g,
    const float* __restrict__ be, unsigned short* __restrict__ out) {
  __shared__ float rs_[4], rq_[4];
  ln_body(x, g, be, out, blockIdx.x, rs_, rq_);
}

// ---------------------------------------------------------------------------
// Fused prelude: blocks [0,3072) = weight transpose; [3072,7168) = LN1 rows.
// ---------------------------------------------------------------------------
__global__ __launch_bounds__(256) void prep_kernel(
    const float* __restrict__ x, const float* __restrict__ g1,
    const float* __restrict__ be1, unsigned short* __restrict__ lnout,
    const float* __restrict__ Wq, const float* __restrict__ Wk,
    const float* __restrict__ Wv, const float* __restrict__ Wo,
    const float* __restrict__ W1, const float* __restrict__ W2,
    unsigned short* __restrict__ wqkv_t, unsigned short* __restrict__ wo_t,
    unsigned short* __restrict__ w1_t, unsigned short* __restrict__ w2_t) {
  __shared__ float lds[64][65];
  __shared__ float rs_[4], rq_[4];
  const int t = blockIdx.x;
  if (t >= 3072) {
    ln_body(x, g1, be1, lnout, t - 3072, rs_, rq_);
    return;
  }
  const float* inb; unsigned short* outb; int in_ld, out_ld;
  if (t < 768) {            // wqkv_t[n=which*1024+h*64+kk][d] = W[h][d][kk]
    const int slice = t >> 4, tin = t & 15;
    const int which = slice >> 4, h = slice & 15;
    const float* W = (which == 0) ? Wq : (which == 1) ? Wk : Wv;
    inb = W + (size_t)((h << 10) + (tin << 6)) * 64;
    in_ld = 64;
    outb = wqkv_t + ((size_t)((which << 10) + (h << 6)) << 10) + (tin << 6);
    out_ld = 1024;
  } else if (t < 1024) {    // wo_t[n][d] = Wo[d][n]
    const int tt = t - 768, tr = tt >> 4, tc = tt & 15;
    inb = Wo + (size_t)(tc << 6) * 1024 + (tr << 6); in_ld = 1024;
    outb = wo_t + (size_t)(tr << 6) * 1024 + (tc << 6); out_ld = 1024;
  } else if (t < 2048) {    // w1_t[n(4096)][d] = W1[d][n]
    const int tt = t - 1024, tr = tt >> 4, tc = tt & 15;
    inb = W1 + (size_t)(tc << 6) * 4096 + (tr << 6); in_ld = 4096;
    outb = w1_t + (size_t)(tr << 6) * 1024 + (tc << 6); out_ld = 1024;
  } else {                  // w2_t[n(1024)][s(4096)] = W2[s][n]
    const int tt = t - 2048, tr = tt >> 6, tc = tt & 63;
    inb = W2 + (size_t)(tc << 6) * 1024 + (tr << 6); in_ld = 1024;
    outb = w2_t + (size_t)(tr << 6) * 4096 + (tc << 6); out_ld = 4096;
  }
  const int j = threadIdx.x & 63, i0 = threadIdx.x >> 6;
#pragma unroll
  for (int p = 0; p < 16; ++p) {
    const int i = i0 + p * 4;
    lds[j][i] = inb[(size_t)i * in_ld + j];
  }
  __syncthreads();
#pragma unroll
  for (int p = 0; p < 16; ++p) {
    const int r = i0 + p * 4;
    outb[(size_t)r * out_ld + j] = f2bf(lds[r][j]);
  }
}

// ---------------------------------------------------------------------------
struct EpiArgs {
  unsigned short* q;     // EPI0 (frag-stream)
  unsigned short* k;     // EPI0 (frag-stream)
  unsigned short* vt;    // EPI0 (frag-stream, kv bit2<->3 folded)
  unsigned short* ob16;  // EPI2
  float* of32;           // EPI1 / EPI4(z=1)
  float* p0;             // EPI4(z=0) fp32 partial
  const float* bias;     // EPI2 / EPI4
  const float* resid;    // EPI1
};

template <int EPI>
DEV void epilogue_elem(float v, int row, int col, int N, int bz,
                       const EpiArgs& ep) {
  if constexpr (EPI == 0) {  // QKV -> fragment-stream scratch layouts
    const int bb = row >> 11, rr = row & 2047;
    if (col < 1024) {        // Q (pre-scaled by log2e/sqrt(dk) -> exp2 domain)
      const int hh = col >> 6, dk = col & 63;
      const int kk = dk >> 4, h8 = (dk >> 3) & 1, e = dk & 7;
      const int qblk = rr >> 5, l31 = rr & 31;
      ep.q[((size_t)(bb * NH + hh) * 64 + qblk) * 2048 + kk * 512 +
           (h8 * 32 + l31) * 8 + e] = f2bf(v * 0.18033688011112042f);
    } else if (col < 2048) { // K
      const int c = col - 1024;
      const int hh = c >> 6, dk = c & 63;
      const int kk = dk >> 4, h8 = (dk >> 3) & 1, e = dk & 7;
      const int kvblk = rr >> 5, l31 = rr & 31;
      ep.k[((size_t)(bb * NH + hh) * 64 + kvblk) * 2048 + kk * 512 +
           (h8 * 32 + l31) * 8 + e] = f2bf(v);
    } else {                 // V (kv bit2<->3 swizzle folded in)
      const int c = col - 2048, hh = c >> 6, dd = c & 63;
      const int ssw = (rr & ~12) | ((rr & 4) << 1) | ((rr & 8) >> 1);
      const int t64 = ssw >> 6, w = (ssw >> 4) & 3;
      const int h8 = (ssw >> 3) & 1, e = ssw & 7;
      const int dblk = dd >> 5, l31 = dd & 31;
      ep.vt[(((size_t)(bb * NH + hh) * 32 + t64) * 8 + dblk * 4 + w) * 512 +
            (h8 * 32 + l31) * 8 + e] = f2bf(v);
    }
  } else if constexpr (EPI == 1) {  // Wo: + residual -> fp32 (x2 into d_out)
    const size_t idx = (size_t)row * N + col;
    ep.of32[idx] = v + ep.resid[idx];
  } else if constexpr (EPI == 2) {  // + bias, exact GELU (A&S poly) -> bf16
    ep.ob16[(size_t)row * N + col] = f2bf(fast_gelu(v + ep.bias[col]));
  } else {  // EPI 4: FFN2 split-K. z=0 -> fp32 partial; z=1 -> out += v+bias
    const size_t idx = (size_t)row * N + col;
    if (bz == 0) ep.p0[idx] = v;
    else ep.of32[idx] = ep.of32[idx] + v + ep.bias[col];
  }
}

// ---------------------------------------------------------------------------
// gemm_256 (R20): 256x256 tile, 8 waves, BK=64, 2-tile prefetch lead,
// 4 compute phases (Q0..Q3), tile T's P4 stages tile T+2.
// ---------------------------------------------------------------------------
template <int EPI>
__global__ __launch_bounds__(512, 2) void gemm_256(
    const unsigned short* __restrict__ A, const unsigned short* __restrict__ Bt,
    int N, int K, int ldk, EpiArgs ep) {
  __shared__ __align__(16) unsigned short Als[2][256 * 64];
  __shared__ __align__(16) unsigned short Bls[2][256 * 64];
  const int t = threadIdx.x, lane = t & 63, wave = t >> 6;
  const int wm = wave >> 2, wn = wave & 3;
  const int g = lane >> 4, r16 = lane & 15;
  const int nx = gridDim.x, nwg = nx * gridDim.y;
  int wgid = blockIdx.y * nx + blockIdx.x;
  wgid = (wgid & 7) * (nwg >> 3) + (wgid >> 3);
  const int m0 = (wgid / nx) * 256, n0 = (wgid % nx) * 256;

  f32x4 acc[8][4];
  const f32x4 z4 = {0.f, 0.f, 0.f, 0.f};
#pragma unroll
  for (int i = 0; i < 8; ++i)
#pragma unroll
    for (int j = 0; j < 4; ++j) acc[i][j] = z4;

  auto stage_half = [&](int b, int k0, int h) {
#pragma unroll
    for (int i = 0; i < 2; ++i) {
      const int c = i * 512 + t;
      const int row = c >> 3;
      const int sc = ((c & 7) ^ (row & 7)) * 8;
      const int dofs = ((h & 1) << 13) + (i * 512 + (wave << 6)) * 8;
      if (h < 2)
        gload_lds16(A + (size_t)(m0 + ((h & 1) << 7) + row) * ldk + k0 + sc,
                    &Als[b][dofs]);
      else
        gload_lds16(Bt + (size_t)(n0 + ((h & 1) << 7) + row) * ldk + k0 + sc,
                    &Bls[b][dofs]);
    }
  };
  auto stage_tile = [&](int b, int k0) {
#pragma unroll
    for (int h = 0; h < 4; ++h) stage_half(b, k0, h);
  };

  const int NT = K >> 6;
  stage_tile(0, 0);
  if (NT > 1) {
    stage_tile(1, 64);
    asm volatile("s_waitcnt vmcnt(8)" ::: "memory");
  } else {
    asm volatile("s_waitcnt vmcnt(0)" ::: "memory");
  }
  __builtin_amdgcn_s_barrier();

  bf16x8 Af[4][2], Bl[2][2], Bh[2][2];
  for (int T = 0; T < NT; ++T) {
    const int cur = T & 1;
    // ---- P1: ds_read A-low + B-low; MFMA Q0 ----
#pragma unroll
    for (int mf = 0; mf < 4; ++mf) {
      const int row = (wm << 7) + (mf << 4) + r16;
#pragma unroll
      for (int ks = 0; ks < 2; ++ks)
        Af[mf][ks] = *(const bf16x8*)
            &Als[cur][row * 64 + ((((ks << 2) | g) ^ (row & 7)) << 3)];
    }
#pragma unroll
    for (int ni = 0; ni < 2; ++ni) {
      const int row = (wn << 6) + (ni << 4) + r16;
#pragma unroll
      for (int ks = 0; ks < 2; ++ks)
        Bl[ni][ks] = *(const bf16x8*)
            &Bls[cur][row * 64 + ((((ks << 2) | g) ^ (row & 7)) << 3)];
    }
    asm volatile("s_waitcnt lgkmcnt(0)" ::: "memory");
    __builtin_amdgcn_sched_barrier(0);
    __builtin_amdgcn_s_setprio(1);
#pragma unroll
    for (int ks = 0; ks < 2; ++ks)
#pragma unroll
      for (int mf = 0; mf < 4; ++mf)
#pragma unroll
        for (int ni = 0; ni < 2; ++ni)
          acc[mf][ni] = __builtin_amdgcn_mfma_f32_16x16x32_bf16(
              Af[mf][ks], Bl[ni][ks], acc[mf][ni], 0, 0, 0);
    __builtin_amdgcn_s_setprio(0);
    __builtin_amdgcn_s_barrier();
    // ---- P2: ds_read B-high; MFMA Q1 ----
#pragma unroll
    for (int ni = 0; ni < 2; ++ni) {
      const int row = (wn << 6) + ((2 + ni) << 4) + r16;
#pragma unroll
      for (int ks = 0; ks < 2; ++ks)
        Bh[ni][ks] = *(const bf16x8*)
            &Bls[cur][row * 64 + ((((ks << 2) | g) ^ (row & 7)) << 3)];
    }
    asm volatile("s_waitcnt lgkmcnt(0)" ::: "memory");
    __builtin_amdgcn_sched_barrier(0);
    __builtin_amdgcn_s_setprio(1);
#pragma unroll
    for (int ks = 0; ks < 2; ++ks)
#pragma unroll
      for (int mf = 0; mf < 4; ++mf)
#pragma unroll
        for (int ni = 0; ni < 2; ++ni)
          acc[mf][2 + ni] = __builtin_amdgcn_mfma_f32_16x16x32_bf16(
              Af[mf][ks], Bh[ni][ks], acc[mf][2 + ni], 0, 0, 0);
    __builtin_amdgcn_s_setprio(0);
    __builtin_amdgcn_s_barrier();
    // ---- P3: ds_read A-high (overwrites Af); MFMA Q2 ----
#pragma unroll
    for (int mf = 0; mf < 4; ++mf) {
      const int row = (wm << 7) + ((4 + mf) << 4) + r16;
#pragma unroll
      for (int ks = 0; ks < 2; ++ks)
        Af[mf][ks] = *(const bf16x8*)
            &Als[cur][row * 64 + ((((ks << 2) | g) ^ (row & 7)) << 3)];
    }
    asm volatile("s_waitcnt lgkmcnt(0)" ::: "memory");
    __builtin_amdgcn_sched_barrier(0);
    __builtin_amdgcn_s_setprio(1);
#pragma unroll
    for (int ks = 0; ks < 2; ++ks)
#pragma unroll
      for (int mf = 0; mf < 4; ++mf)
#pragma unroll
        for (int ni = 0; ni < 2; ++ni)
          acc[4 + mf][ni] = __builtin_amdgcn_mfma_f32_16x16x32_bf16(
              Af[mf][ks], Bl[ni][ks], acc[4 + mf][ni], 0, 0, 0);
    __builtin_amdgcn_s_setprio(0);
    __builtin_amdgcn_s_barrier();
    // ---- P4: issue tile T+2 (into T's buffer); MFMA Q3 ----
    if (T + 2 < NT) stage_tile(cur, (T + 2) << 6);
    __builtin_amdgcn_s_setprio(1);
#pragma unroll
    for (int ks = 0; ks < 2; ++ks)
#pragma unroll
      for (int mf = 0; mf < 4; ++mf)
#pragma unroll
        for (int ni = 0; ni < 2; ++ni)
          acc[4 + mf][2 + ni] = __builtin_amdgcn_mfma_f32_16x16x32_bf16(
              Af[mf][ks], Bh[ni][ks], acc[4 + mf][2 + ni], 0, 0, 0);
    __builtin_amdgcn_s_setprio(0);
    if (T + 1 < NT)
      asm volatile("s_waitcnt vmcnt(8)" ::: "memory");
    __builtin_amdgcn_s_barrier();
  }
#pragma unroll
  for (int mf = 0; mf < 8; ++mf)
#pragma unroll
    for (int nf = 0; nf < 4; ++nf)
#pragma unroll
      for (int r = 0; r < 4; ++r)
        epilogue_elem<EPI>(acc[mf][nf][r],
                           m0 + (wm << 7) + (mf << 4) + (g << 2) + r,
                           n0 + (wn << 6) + (nf << 4) + r16, N, 0, ep);
}

// ---------------------------------------------------------------------------
// Pipelined GEMM (128^2 tile, BK=64, LDS dbuf) -- Wo (single) / FFN2 (z=2).
// R21 deep lead: prologue stages tiles 0,1.  Per tile: vmcnt(8|0) ->
// B1 -> ds_read x16 -> lgkmcnt(0) -> B2 (reads done) -> stage(T+2 into
// buf[cur]) -> 32 MFMA (monolithic).
// ---------------------------------------------------------------------------
template <int EPI>
__global__ __launch_bounds__(256) void gemm_pipe(
    const unsigned short* __restrict__ A, const unsigned short* __restrict__ Bt,
    int N, int Kc, int ldk, EpiArgs ep) {
  __shared__ __align__(16) unsigned short Als[2][128 * 64];
  __shared__ __align__(16) unsigned short Bls[2][128 * 64];
  const int t = threadIdx.x, lane = t & 63, wave = t >> 6;
  const int wm = wave >> 1, wn = wave & 1;
  const int g = lane >> 4, r16 = lane & 15;
  const int nx = gridDim.x;
  const int nwg = nx * gridDim.y;
  int wgid = blockIdx.y * nx + blockIdx.x;
  wgid = (wgid & 7) * (nwg >> 3) + (wgid >> 3);
  const int m0 = (wgid / nx) * 128, n0 = (wgid % nx) * 128;
  const int kbase = blockIdx.z * Kc;

  f32x4 acc[4][4];
  const f32x4 z4 = {0.f, 0.f, 0.f, 0.f};
#pragma unroll
  for (int i = 0; i < 4; ++i)
#pragma unroll
    for (int j = 0; j < 4; ++j) acc[i][j] = z4;

  auto stage = [&](int b, int k0) {
#pragma unroll
    for (int i = 0; i < 4; ++i) {
      const int cb = i * 256 + wave * 64;
      const int c = cb + lane;
      const int row = c >> 3;
      const int sc = ((c & 7) ^ (row & 7)) * 8;
      gload_lds16(A + (size_t)(m0 + row) * ldk + kbase + k0 + sc, &Als[b][cb * 8]);
      gload_lds16(Bt + (size_t)(n0 + row) * ldk + kbase + k0 + sc, &Bls[b][cb * 8]);
    }
  };

  const int NT = Kc >> 6;
  stage(0, 0);
  if (NT > 1) stage(1, 64);           // 16 loads in flight (tiles 0,1)
  for (int kt = 0; kt < NT; ++kt) {
    const int cur = kt & 1;
    if (kt + 1 < NT)
      asm volatile("s_waitcnt vmcnt(8)" ::: "memory");  // tile kt landed
    else
      asm volatile("s_waitcnt vmcnt(0)" ::: "memory");  // last: drain all
    __builtin_amdgcn_s_barrier();     // B1: tile kt visible to all waves
    __builtin_amdgcn_sched_barrier(0);

    const int sw = r16 & 7;
    bf16x8 af[2][4], bfr[2][4];
#pragma unroll
    for (int ks = 0; ks < 2; ++ks) {
#pragma unroll
      for (int mt = 0; mt < 4; ++mt)
        af[ks][mt] = *(const bf16x8*)&Als[cur][(wm * 64 + mt * 16 + r16) * 64 +
                                              (((ks << 2) | g) ^ sw) * 8];
#pragma unroll
      for (int nt = 0; nt < 4; ++nt)
        bfr[ks][nt] = *(const bf16x8*)&Bls[cur][(wn * 64 + nt * 16 + r16) * 64 +
                                               (((ks << 2) | g) ^ sw) * 8];
    }
    asm volatile("s_waitcnt lgkmcnt(0)" ::: "memory");
    __builtin_amdgcn_sched_barrier(0);
    __builtin_amdgcn_s_barrier();     // B2: all waves' reads of buf[cur] done
    if (kt + 2 < NT) stage(cur, (kt + 2) << 6);  // overwrite in MFMA shadow

    __builtin_amdgcn_s_setprio(1);
#pragma unroll
    for (int ks = 0; ks < 2; ++ks)
#pragma unroll
      for (int mt = 0; mt < 4; ++mt)
#pragma unroll
        for (int nt = 0; nt < 4; ++nt)
          acc[mt][nt] = __builtin_amdgcn_mfma_f32_16x16x32_bf16(
              af[ks][mt], bfr[ks][nt], acc[mt][nt], 0, 0, 0);
    __builtin_amdgcn_s_setprio(0);
  }
#pragma unroll
  for (int mt = 0; mt < 4; ++mt)
#pragma unroll
    for (int nt = 0; nt < 4; ++nt)
#pragma unroll
      for (int r = 0; r < 4; ++r)
        epilogue_elem<EPI>(acc[mt][nt][r], m0 + wm * 64 + mt * 16 + g * 4 + r,
                           n0 + wn * 64 + nt * 16 + r16, N, blockIdx.z, ep);
}

// ---------------------------------------------------------------------------
__global__ __launch_bounds__(256) void reduce_add(const float* __restrict__ p,
                                                  float* __restrict__ out) {
  const int i = blockIdx.x * 256 + threadIdx.x;
  float4 a = ((const float4*)p)[i];
  float4 b = ((float4*)out)[i];
  b.x += a.x; b.y += a.y; b.z += a.z; b.w += a.w;
  ((float4*)out)[i] = b;
}

// ---------------------------------------------------------------------------
// Flash attention (R24): R10 compute, K/V LDS-staged per block (4 waves
// share the (b,h) K/V).  Per 64-kv tile: 8KB K + 8KB V contiguous in the
// frag-stream -> double-buffered LDS via global_load_lds, R21 schedule:
// vmcnt(4|0) -> B1 -> 16 ds_read -> lgkmcnt(0) -> B2 -> stage(t+2) ->
// compute (QK/softmax/PV unchanged).
// ---------------------------------------------------------------------------
struct AttnState {
  f32x16 o0, o1;
  float m, lsum;
};

DEV void attn_tile(const bf16x8 k0[4], const bf16x8 k1[4],
                   const bf16x8 v0[4], const bf16x8 v1[4],
                   const bf16x8 qf[4], AttnState& st) {
  const f32x16 z16 = {0.f};
  f32x16 pA = z16, pB = z16;
  __builtin_amdgcn_s_setprio(1);
#pragma unroll
  for (int kk = 0; kk < 4; ++kk) {
    pA = __builtin_amdgcn_mfma_f32_32x32x16_bf16(k0[kk], qf[kk], pA, 0, 0, 0);
    pB = __builtin_amdgcn_mfma_f32_32x32x16_bf16(k1[kk], qf[kk], pB, 0, 0, 0);
  }
  __builtin_amdgcn_s_setprio(0);
  float m0 = fmaxf(pA[0], pB[0]), m1 = fmaxf(pA[1], pB[1]);
  float m2 = fmaxf(pA[2], pB[2]), m3 = fmaxf(pA[3], pB[3]);
#pragma unroll
  for (int r = 4; r < 16; r += 4) {
    m0 = fmaxf(m0, fmaxf(pA[r + 0], pB[r + 0]));
    m1 = fmaxf(m1, fmaxf(pA[r + 1], pB[r + 1]));
    m2 = fmaxf(m2, fmaxf(pA[r + 2], pB[r + 2]));
    m3 = fmaxf(m3, fmaxf(pA[r + 3], pB[r + 3]));
  }
  float mx = fmaxf(fmaxf(m0, m1), fmaxf(m2, m3));
  mx = fmaxf(mx, __shfl_xor(mx, 32));
  if (__any(mx > st.m + 11.5416f)) {  // defer-max, exp2 domain (8*log2e)
    const float mnew = fmaxf(st.m, mx);
    const float corr = __builtin_amdgcn_exp2f(st.m - mnew);
#pragma unroll
    for (int r = 0; r < 16; ++r) { st.o0[r] *= corr; st.o1[r] *= corr; }
    st.lsum *= corr;
    st.m = mnew;
  }
  float ps = 0.f;
#pragma unroll
  for (int r = 0; r < 16; ++r) {
    pA[r] = __builtin_amdgcn_exp2f(pA[r] - st.m); ps += pA[r];
    pB[r] = __builtin_amdgcn_exp2f(pB[r] - st.m); ps += pB[r];
  }
  ps += __shfl_xor(ps, 32);
  st.lsum += ps;
  bf16x8 pw[4];
#pragma unroll
  for (int w = 0; w < 4; ++w) {
    unsigned int wd0, wd1, wd2, wd3;
    const int e0 = (w & 1) * 8;
    if (w < 2) {
      asm("v_cvt_pk_bf16_f32 %0, %1, %2" : "=v"(wd0) : "v"(pA[e0 + 0]), "v"(pA[e0 + 1]));
      asm("v_cvt_pk_bf16_f32 %0, %1, %2" : "=v"(wd1) : "v"(pA[e0 + 2]), "v"(pA[e0 + 3]));
      asm("v_cvt_pk_bf16_f32 %0, %1, %2" : "=v"(wd2) : "v"(pA[e0 + 4]), "v"(pA[e0 + 5]));
      asm("v_cvt_pk_bf16_f32 %0, %1, %2" : "=v"(wd3) : "v"(pA[e0 + 6]), "v"(pA[e0 + 7]));
    } else {
      asm("v_cvt_pk_bf16_f32 %0, %1, %2" : "=v"(wd0) : "v"(pB[e0 + 0]), "v"(pB[e0 + 1]));
      asm("v_cvt_pk_bf16_f32 %0, %1, %2" : "=v"(wd1) : "v"(pB[e0 + 2]), "v"(pB[e0 + 3]));
      asm("v_cvt_pk_bf16_f32 %0, %1, %2" : "=v"(wd2) : "v"(pB[e0 + 4]), "v"(pB[e0 + 5]));
      asm("v_cvt_pk_bf16_f32 %0, %1, %2" : "=v"(wd3) : "v"(pB[e0 + 6]), "v"(pB[e0 + 7]));
    }
    u32x4 wv = {wd0, wd1, wd2, wd3};
    pw[w] = __builtin_bit_cast(bf16x8, wv);
  }
  __builtin_amdgcn_s_setprio(1);
#pragma unroll
  for (int w = 0; w < 4; ++w) {
    st.o0 = __builtin_amdgcn_mfma_f32_32x32x16_bf16(v0[w], pw[w], st.o0, 0, 0, 0);
    st.o1 = __builtin_amdgcn_mfma_f32_32x32x16_bf16(v1[w], pw[w], st.o1, 0, 0, 0);
  }
  __builtin_amdgcn_s_setprio(0);
}

__global__ __launch_bounds__(256, 2) void attn_kernel(
    const unsigned short* __restrict__ Qc, const unsigned short* __restrict__ Kc,
    const unsigned short* __restrict__ Vt, unsigned short* __restrict__ Oc) {
  __shared__ __align__(16) unsigned short Klds[2][4096];
  __shared__ __align__(16) unsigned short Vlds[2][4096];
  const int lane = threadIdx.x & 63, wave = threadIdx.x >> 6;
  const int hi = lane >> 5, l31 = lane & 31;
  const int i = blockIdx.x;
  const int k8 = i & 7, mq = i >> 3;
  const int grp = k8 + 8 * (mq >> 4);
  const int qb = mq & 15;
  const int b = grp >> 4, h = grp & 15;
  const int q0 = qb * 128 + wave * 32;

  const unsigned short* qbp = Qc + ((size_t)grp * 64 + (q0 >> 5)) * 2048 + lane * 8;
  const unsigned short* Kg = Kc + (size_t)grp * 131072;  // (b,h) K stream
  const unsigned short* Vg = Vt + (size_t)grp * 131072;  // (b,h) V stream

  bf16x8 qf[4];
#pragma unroll
  for (int kk = 0; kk < 4; ++kk) qf[kk] = *(const bf16x8*)(qbp + kk * 512);

  AttnState st;
#pragma unroll
  for (int r = 0; r < 16; ++r) { st.o0[r] = 0.f; st.o1[r] = 0.f; }
  st.m = -1e30f; st.lsum = 0.f;

  // stage tile (64 kv = 4096 contiguous elements in both streams) into LDS.
  // 4 gload_lds16 per thread (2 K + 2 V).
  auto stage = [&](int buf, int tile) {
    const size_t off = (size_t)tile * 4096;
#pragma unroll
    for (int j = 0; j < 2; ++j) {
      const int c = j * 256 + threadIdx.x;           // 16B chunk index
      const int db = (j * 256 + wave * 64) * 8;      // wave-uniform LDS base
      gload_lds16(Kg + off + c * 8, &Klds[buf][db]);
      gload_lds16(Vg + off + c * 8, &Vlds[buf][db]);
    }
  };

  stage(0, 0);
  stage(1, 1);
  for (int t = 0; t < 32; ++t) {
    const int cur = t & 1;
    if (t + 1 < 32)
      asm volatile("s_waitcnt vmcnt(4)" ::: "memory");  // tile t landed
    else
      asm volatile("s_waitcnt vmcnt(0)" ::: "memory");
    __builtin_amdgcn_s_barrier();     // B1: tile t visible to all waves
    __builtin_amdgcn_sched_barrier(0);

    bf16x8 k0[4], k1[4], v0[4], v1[4];
#pragma unroll
    for (int kk = 0; kk < 4; ++kk) {
      k0[kk] = *(const bf16x8*)&Klds[cur][kk * 512 + lane * 8];
      k1[kk] = *(const bf16x8*)&Klds[cur][2048 + kk * 512 + lane * 8];
    }
#pragma unroll
    for (int w = 0; w < 4; ++w) {
      v0[w] = *(const bf16x8*)&Vlds[cur][w * 512 + lane * 8];
      v1[w] = *(const bf16x8*)&Vlds[cur][2048 + w * 512 + lane * 8];
    }
    asm volatile("s_waitcnt lgkmcnt(0)" ::: "memory");
    __builtin_amdgcn_sched_barrier(0);
    __builtin_amdgcn_s_barrier();     // B2: all waves' reads of buf[cur] done
    if (t + 2 < 32) stage(cur, t + 2);  // overwrite in compute shadow

    attn_tile(k0, k1, v0, v1, qf, st);
  }

  const float inv = 1.0f / st.lsum;
  const size_t rowbase = (size_t)b * SEQ;
  unsigned short* op = Oc + (rowbase + q0 + l31) * DM + h * DKH + hi * 4;
#pragma unroll
  for (int dblk = 0; dblk < 2; ++dblk)
#pragma unroll
    for (int g4 = 0; g4 < 4; ++g4) {
      u16x4 stv;
#pragma unroll
      for (int r = 0; r < 4; ++r) {
        const float v = (dblk ? st.o1[g4 * 4 + r] : st.o0[g4 * 4 + r]) * inv;
        stv[r] = f2bf(v);
      }
      *(u16x4*)(op + dblk * 32 + g4 * 8) = stv;
    }
}

// ---------------------------------------------------------------------------
extern "C" void kernel_launch(void* const* d_in, const int* in_sizes, int n_in,
                              void* d_out, int out_size, void* d_ws,
                              size_t ws_size, hipStream_t stream) {
  (void)in_sizes; (void)n_in; (void)out_size; (void)ws_size;
  const float* x   = (const float*)d_in[0];
  const float* Wq  = (const float*)d_in[1];
  const float* Wk  = (const float*)d_in[2];
  const float* Wv  = (const float*)d_in[3];
  const float* Wo  = (const float*)d_in[4];
  const float* W1  = (const float*)d_in[5];
  const float* b1  = (const float*)d_in[6];
  const float* W2  = (const float*)d_in[7];
  const float* b2  = (const float*)d_in[8];
  const float* g1  = (const float*)d_in[9];
  const float* be1 = (const float*)d_in[10];
  const float* g2  = (const float*)d_in[11];
  const float* be2 = (const float*)d_in[12];
  float* out = (float*)d_out;

  char* ws = (char*)d_ws;
  const size_t MB = 1024 * 1024;
  unsigned short* h_buf  = (unsigned short*)(ws + 0 * MB);
  unsigned short* wqkv_t = (unsigned short*)(ws + 8 * MB);
  unsigned short* wo_t   = (unsigned short*)(ws + 14 * MB);
  unsigned short* w1_t   = (unsigned short*)(ws + 16 * MB);
  unsigned short* w2_t   = (unsigned short*)(ws + 24 * MB);
  unsigned short* q_attn = (unsigned short*)(ws + 32 * MB);
  unsigned short* k_attn = (unsigned short*)(ws + 40 * MB);
  unsigned short* v_attn = (unsigned short*)(ws + 48 * MB);
  unsigned short* ffn1   = (unsigned short*)(ws + 32 * MB);  // overlaps q/k/v
  float*          p0     = (float*)(ws + 0 * MB);  // 16MB; dead bufs @FFN2

  EpiArgs e0 = {}; e0.q = q_attn; e0.k = k_attn; e0.vt = v_attn;
  EpiArgs e1 = {}; e1.of32 = out; e1.resid = x;
  EpiArgs e2 = {}; e2.ob16 = ffn1; e2.bias = b1;
  EpiArgs e4 = {}; e4.of32 = out; e4.p0 = p0; e4.bias = b2;

  prep_kernel<<<3072 + NTOK, 256, 0, stream>>>(
      x, g1, be1, h_buf, Wq, Wk, Wv, Wo, W1, W2, wqkv_t, wo_t, w1_t, w2_t);
  gemm_256<0><<<dim3(3072 / 256, NTOK / 256), 512, 0, stream>>>(
      h_buf, wqkv_t, 3072, DM, DM, e0);
  attn_kernel<<<512, 256, 0, stream>>>(q_attn, k_attn, v_attn, h_buf);
  gemm_pipe<1><<<dim3(DM / 128, NTOK / 128, 1), 256, 0, stream>>>(
      h_buf, wo_t, DM, DM, DM, e1);
  ln_kernel<<<NTOK, 256, 0, stream>>>(out, g2, be2, h_buf);
  gemm_256<2><<<dim3(DFF / 256, NTOK / 256), 512, 0, stream>>>(
      h_buf, w1_t, DFF, DM, DM, e2);
  gemm_pipe<4><<<dim3(DM / 128, NTOK / 128, 2), 256, 0, stream>>>(
      ffn1, w2_t, DM, DFF / 2, DFF, e4);
  reduce_add<<<4096, 256, 0, stream>>>(p0, out);
}